// Round 1
// baseline (709.925 us; speedup 1.0000x reference)
//
#include <hip/hip_runtime.h>
#include <hip/hip_bf16.h>

#define BB 4
#define CC 256
#define NN 4096
#define NGROUPS 32
#define CPG 8
#define EPSG 1e-6f
#define SCALE 0.0625f                 // C^-0.5
#define KLS 0.09016844005556021f      // SCALE * log2(e)

typedef __bf16 bf16x8 __attribute__((ext_vector_type(8)));
typedef float  f32x4  __attribute__((ext_vector_type(4)));

__device__ __forceinline__ unsigned short f2bf(float f) {
  unsigned u = __builtin_bit_cast(unsigned, f);
  u += 0x7fffu + ((u >> 16) & 1u);
  return (unsigned short)(u >> 16);
}

__device__ __forceinline__ f32x4 mfma16(bf16x8 a, bf16x8 b, f32x4 c) {
  return __builtin_amdgcn_mfma_f32_16x16x32_bf16(a, b, c, 0, 0, 0);
}

__device__ __forceinline__ bf16x8 ldfrag(const unsigned short* p) {
  return __builtin_bit_cast(bf16x8, *(const uint4*)p);
}

// ---- weights fp32 -> bf16 ----
__global__ __launch_bounds__(256) void wcvt(const float* __restrict__ wq,
    const float* __restrict__ wk, const float* __restrict__ wv,
    const float* __restrict__ wo, unsigned short* __restrict__ out) {
  int mat = blockIdx.y;
  const float* s = mat == 0 ? wq : mat == 1 ? wk : mat == 2 ? wv : wo;
  int i = (blockIdx.x * 256 + threadIdx.x) * 4;
  float4 v = *(const float4*)&s[i];
  unsigned short* d = out + (size_t)mat * CC * CC + i;
  d[0] = f2bf(v.x); d[1] = f2bf(v.y); d[2] = f2bf(v.z); d[3] = f2bf(v.w);
}

// ---- GroupNorm, writes xn transposed [b][n][c] as bf16 ----
__global__ __launch_bounds__(256) void gnorm(const float* __restrict__ x,
    const float* __restrict__ gw, const float* __restrict__ gb,
    unsigned short* __restrict__ xnT) {
  int b = blockIdx.x / NGROUPS, g = blockIdx.x % NGROUPS;
  const float* xp = x + ((size_t)b * CC + g * CPG) * NN;
  int tid = threadIdx.x;
  float s = 0.f, s2 = 0.f;
  for (int i = tid; i < CPG * NN; i += 256) {
    float v = xp[i];
    s += v; s2 += v * v;
  }
  for (int o = 32; o; o >>= 1) { s += __shfl_down(s, o); s2 += __shfl_down(s2, o); }
  __shared__ float rs[4], rs2[4];
  int wid = tid >> 6, lane = tid & 63;
  if (lane == 0) { rs[wid] = s; rs2[wid] = s2; }
  __syncthreads();
  if (tid == 0) {
    float a = rs[0] + rs[1] + rs[2] + rs[3];
    float a2 = rs2[0] + rs2[1] + rs2[2] + rs2[3];
    float mean = a / (CPG * NN);
    float var = a2 / (CPG * NN) - mean * mean;
    rs[0] = mean; rs2[0] = rsqrtf(var + EPSG);
  }
  __syncthreads();
  float mean = rs[0], inv = rs2[0];
  for (int i = tid; i < CPG * NN; i += 256) {
    int c = g * CPG + (i >> 12);
    int n = i & (NN - 1);
    float v = (xp[i] - mean) * inv * gw[c] + gb[c];
    xnT[((size_t)b * NN + n) * CC + c] = f2bf(v);
  }
}

// ---- QKV projections: qT/kT [b][n][o], v [b][o][n] ----
__global__ __launch_bounds__(256) void qkv(const unsigned short* __restrict__ xnT,
    const unsigned short* __restrict__ wbf,
    const float* __restrict__ bq, const float* __restrict__ bk,
    const float* __restrict__ bv,
    unsigned short* __restrict__ qT, unsigned short* __restrict__ kT,
    unsigned short* __restrict__ vm) {
  const int b = blockIdx.x >> 6, nt = blockIdx.x & 63;
  const int n0 = nt * 64;
  __shared__ unsigned short Xs[64][CC + 8];
  int tid = threadIdx.x;
  for (int i = 0; i < 8; ++i) {
    int id = tid + 256 * i;
    int r = id >> 5, ck = id & 31;
    *(uint4*)&Xs[r][ck * 8] = *(const uint4*)&xnT[((size_t)b * NN + n0 + r) * CC + ck * 8];
  }
  __syncthreads();
  int w = tid >> 6, lane = tid & 63;
  int m = lane & 15, q4 = lane >> 4;
  int r0 = w * 16;
  bf16x8 xa[8];
  for (int k = 0; k < 8; ++k)
    xa[k] = ldfrag(&Xs[r0 + m][k * 32 + q4 * 8]);
  const unsigned short* Wq = wbf;
  const unsigned short* Wk = wbf + CC * CC;
  const unsigned short* Wv = wbf + 2 * CC * CC;
  for (int sel = 0; sel < 2; ++sel) {
    const unsigned short* W = sel ? Wk : Wq;
    const float* bias = sel ? bk : bq;
    unsigned short* dst = sel ? kT : qT;
    for (int ot = 0; ot < 16; ++ot) {
      f32x4 acc = {0.f, 0.f, 0.f, 0.f};
      for (int k = 0; k < 8; ++k) {
        bf16x8 bf = ldfrag(&W[(size_t)(ot * 16 + m) * CC + k * 32 + q4 * 8]);
        acc = mfma16(xa[k], bf, acc);
      }
      int o = ot * 16 + m;
      float bia = bias[o];
      for (int r = 0; r < 4; ++r) {
        int n = n0 + r0 + q4 * 4 + r;
        dst[((size_t)b * NN + n) * CC + o] = f2bf(acc[r] + bia);
      }
    }
  }
  // v[o][n]
  for (int ot = 0; ot < 4; ++ot) {
    int o0 = w * 64 + ot * 16;
    bf16x8 af[8];
    for (int k = 0; k < 8; ++k)
      af[k] = ldfrag(&Wv[(size_t)(o0 + m) * CC + k * 32 + q4 * 8]);
    for (int nt4 = 0; nt4 < 4; ++nt4) {
      f32x4 acc = {0.f, 0.f, 0.f, 0.f};
      for (int k = 0; k < 8; ++k) {
        bf16x8 bfr = ldfrag(&Xs[nt4 * 16 + m][k * 32 + q4 * 8]);
        acc = mfma16(af[k], bfr, acc);
      }
      int n = n0 + nt4 * 16 + m;
      float bia = bv[0];
      for (int r = 0; r < 4; ++r) {
        int o = o0 + q4 * 4 + r;
        vm[((size_t)b * CC + o) * NN + n] = f2bf(acc[r] + bv[o]);
      }
      (void)bia;
    }
  }
}

// ---- flash attention: oT [b][i][c] ----
__global__ __launch_bounds__(256) void attn(const unsigned short* __restrict__ qT,
    const unsigned short* __restrict__ kT, const unsigned short* __restrict__ vm,
    unsigned short* __restrict__ oT) {
  const int b = blockIdx.x >> 6, it = blockIdx.x & 63;
  const int i0 = it * 64;
  __shared__ unsigned short Ks[64][CC + 8];       // K rows j, cols c
  __shared__ unsigned short Vs[CC][64 + 8];       // V rows c, cols j
  __shared__ unsigned short Ps[4][16][64 + 8];    // per-wave P [i][j]
  int tid = threadIdx.x, w = tid >> 6, lane = tid & 63;
  int m = lane & 15, q4 = lane >> 4;
  bf16x8 qa[8];
  for (int k = 0; k < 8; ++k)
    qa[k] = ldfrag(&qT[((size_t)b * NN + i0 + w * 16 + m) * CC + k * 32 + q4 * 8]);
  f32x4 acc[16];
  for (int i = 0; i < 16; ++i) acc[i] = (f32x4){0.f, 0.f, 0.f, 0.f};
  float mrow[4] = {-1e30f, -1e30f, -1e30f, -1e30f};
  float lrow[4] = {0.f, 0.f, 0.f, 0.f};
  for (int jt = 0; jt < 64; ++jt) {
    int j0 = jt * 64;
    for (int i = 0; i < 8; ++i) {
      int id = tid + 256 * i;
      int r = id >> 5, ck = id & 31;
      *(uint4*)&Ks[r][ck * 8] = *(const uint4*)&kT[((size_t)b * NN + j0 + r) * CC + ck * 8];
    }
    for (int i = 0; i < 8; ++i) {
      int id = tid + 256 * i;
      int c = id >> 3, ck = id & 7;
      *(uint4*)&Vs[c][ck * 8] = *(const uint4*)&vm[((size_t)b * CC + c) * NN + j0 + ck * 8];
    }
    __syncthreads();
    f32x4 s[4];
    for (int jt4 = 0; jt4 < 4; ++jt4) {
      f32x4 a = {0.f, 0.f, 0.f, 0.f};
      for (int k = 0; k < 8; ++k) {
        bf16x8 kf = ldfrag(&Ks[jt4 * 16 + m][k * 32 + q4 * 8]);
        a = mfma16(qa[k], kf, a);
      }
      s[jt4] = a;
    }
    float mnew[4], alpha[4];
    for (int r = 0; r < 4; ++r) {
      float mx = fmaxf(fmaxf(s[0][r], s[1][r]), fmaxf(s[2][r], s[3][r]));
      for (int o = 8; o; o >>= 1) mx = fmaxf(mx, __shfl_xor(mx, o));
      mnew[r] = fmaxf(mrow[r], mx);
      alpha[r] = exp2f((mrow[r] - mnew[r]) * KLS);
      mrow[r] = mnew[r];
    }
    for (int r = 0; r < 4; ++r) {
      float rsum = 0.f;
      for (int jt4 = 0; jt4 < 4; ++jt4) {
        float p = exp2f((s[jt4][r] - mnew[r]) * KLS);
        rsum += p;
        Ps[w][q4 * 4 + r][jt4 * 16 + m] = f2bf(p);
      }
      for (int o = 8; o; o >>= 1) rsum += __shfl_xor(rsum, o);
      lrow[r] = lrow[r] * alpha[r] + rsum;
    }
    for (int ct = 0; ct < 16; ++ct)
      for (int r = 0; r < 4; ++r) acc[ct][r] *= alpha[r];
    __syncthreads();
    for (int kk = 0; kk < 2; ++kk) {
      bf16x8 pf = ldfrag(&Ps[w][m][kk * 32 + q4 * 8]);
      for (int ct = 0; ct < 16; ++ct) {
        bf16x8 vf = ldfrag(&Vs[ct * 16 + m][kk * 32 + q4 * 8]);
        acc[ct] = mfma16(pf, vf, acc[ct]);
      }
    }
    __syncthreads();
  }
  for (int r = 0; r < 4; ++r) {
    float invl = 1.0f / lrow[r];
    int i = i0 + w * 16 + q4 * 4 + r;
    for (int ct = 0; ct < 16; ++ct) {
      int c = ct * 16 + m;
      oT[((size_t)b * NN + i) * CC + c] = f2bf(acc[ct][r] * invl);
    }
  }
}

// ---- output projection + bias + residual, fp32 out [b][o][n] ----
__global__ __launch_bounds__(256) void proj(const unsigned short* __restrict__ oT,
    const unsigned short* __restrict__ Wo, const float* __restrict__ bo,
    const float* __restrict__ x, float* __restrict__ out) {
  const int b = blockIdx.x >> 6, nt = blockIdx.x & 63;
  const int n0 = nt * 64;
  __shared__ unsigned short As[64][CC + 8];
  int tid = threadIdx.x;
  for (int i = 0; i < 8; ++i) {
    int id = tid + 256 * i;
    int r = id >> 5, ck = id & 31;
    *(uint4*)&As[r][ck * 8] = *(const uint4*)&oT[((size_t)b * NN + n0 + r) * CC + ck * 8];
  }
  __syncthreads();
  int w = tid >> 6, lane = tid & 63, m = lane & 15, q4 = lane >> 4;
  for (int ot = 0; ot < 4; ++ot) {
    int o0 = w * 64 + ot * 16;
    bf16x8 af[8];
    for (int k = 0; k < 8; ++k)
      af[k] = ldfrag(&Wo[(size_t)(o0 + m) * CC + k * 32 + q4 * 8]);
    for (int nt4 = 0; nt4 < 4; ++nt4) {
      f32x4 a = {0.f, 0.f, 0.f, 0.f};
      for (int k = 0; k < 8; ++k) {
        bf16x8 bf = ldfrag(&As[nt4 * 16 + m][k * 32 + q4 * 8]);
        a = mfma16(af[k], bf, a);
      }
      int n = n0 + nt4 * 16 + m;
      for (int r = 0; r < 4; ++r) {
        int o = o0 + q4 * 4 + r;
        size_t idx = ((size_t)b * CC + o) * NN + n;
        out[idx] = x[idx] + bo[o] + a[r];
      }
    }
  }
}

extern "C" void kernel_launch(void* const* d_in, const int* in_sizes, int n_in,
                              void* d_out, int out_size, void* d_ws, size_t ws_size,
                              hipStream_t stream) {
  const float* x  = (const float*)d_in[0];
  const float* gw = (const float*)d_in[1];
  const float* gb = (const float*)d_in[2];
  const float* wq = (const float*)d_in[3];
  const float* bq = (const float*)d_in[4];
  const float* wk = (const float*)d_in[5];
  const float* bk = (const float*)d_in[6];
  const float* wv = (const float*)d_in[7];
  const float* bv = (const float*)d_in[8];
  const float* wo = (const float*)d_in[9];
  const float* bo = (const float*)d_in[10];

  unsigned short* ws  = (unsigned short*)d_ws;
  const size_t M4 = (size_t)BB * NN * CC;   // 4M elems
  unsigned short* xnT = ws;
  unsigned short* qT  = xnT + M4;
  unsigned short* kT  = qT + M4;
  unsigned short* vm  = kT + M4;
  unsigned short* oT  = vm + M4;
  unsigned short* wbf = oT + M4;            // 4 * 65536

  wcvt<<<dim3(64, 4), 256, 0, stream>>>(wq, wk, wv, wo, wbf);
  gnorm<<<BB * NGROUPS, 256, 0, stream>>>(x, gw, gb, xnT);
  qkv<<<BB * (NN / 64), 256, 0, stream>>>(xnT, wbf, bq, bk, bv, qT, kT, vm);
  attn<<<BB * (NN / 64), 256, 0, stream>>>(qT, kT, vm, oT);
  proj<<<BB * (NN / 64), 256, 0, stream>>>(oT, wbf + 3 * CC * CC, bo, x, (float*)d_out);
}

// Round 2
// 505.182 us; speedup vs baseline: 1.4053x; 1.4053x over previous
//
#include <hip/hip_runtime.h>
#include <hip/hip_bf16.h>

#define BB 4
#define CC 256
#define NN 4096
#define BBNN (BB * NN)
#define NGROUPS 32
#define CPG 8
#define EPSG 1e-6f
#define SCALE 0.0625f                 // C^-0.5
#define KLS 0.09016844005556021f      // SCALE * log2(e)
#define KSPLIT 2
#define JITERS (64 / KSPLIT)

typedef __bf16 bf16x8 __attribute__((ext_vector_type(8)));
typedef float  f32x4  __attribute__((ext_vector_type(4)));

__device__ __forceinline__ unsigned short f2bf(float f) {
  unsigned u = __builtin_bit_cast(unsigned, f);
  u += 0x7fffu + ((u >> 16) & 1u);
  return (unsigned short)(u >> 16);
}

__device__ __forceinline__ f32x4 mfma16(bf16x8 a, bf16x8 b, f32x4 c) {
  return __builtin_amdgcn_mfma_f32_16x16x32_bf16(a, b, c, 0, 0, 0);
}

__device__ __forceinline__ bf16x8 ldfrag(const unsigned short* p) {
  return __builtin_bit_cast(bf16x8, *(const uint4*)p);
}

// ---- weights fp32 -> bf16 ----
__global__ __launch_bounds__(256) void wcvt(const float* __restrict__ wq,
    const float* __restrict__ wk, const float* __restrict__ wv,
    const float* __restrict__ wo, unsigned short* __restrict__ out) {
  int mat = blockIdx.y;
  const float* s = mat == 0 ? wq : mat == 1 ? wk : mat == 2 ? wv : wo;
  int i = (blockIdx.x * 256 + threadIdx.x) * 4;
  float4 v = *(const float4*)&s[i];
  unsigned short* d = out + (size_t)mat * CC * CC + i;
  d[0] = f2bf(v.x); d[1] = f2bf(v.y); d[2] = f2bf(v.z); d[3] = f2bf(v.w);
}

// ---- GroupNorm stats: grid 256 = 128 (b,g) pairs x 2 halves ----
__global__ __launch_bounds__(256) void gn_stats(const float* __restrict__ x,
                                                float* __restrict__ part) {
  int pair = blockIdx.x >> 1, h = blockIdx.x & 1;
  const float* xp = x + (size_t)pair * (CPG * NN) + (size_t)h * (CPG * NN / 2);
  float s = 0.f, s2 = 0.f;
  for (int i = threadIdx.x; i < CPG * NN / 8; i += 256) {
    float4 v = ((const float4*)xp)[i];
    s += v.x + v.y + v.z + v.w;
    s2 += v.x * v.x + v.y * v.y + v.z * v.z + v.w * v.w;
  }
  for (int o = 32; o; o >>= 1) { s += __shfl_down(s, o); s2 += __shfl_down(s2, o); }
  __shared__ float rs[4], rs2[4];
  int wid = threadIdx.x >> 6, lane = threadIdx.x & 63;
  if (lane == 0) { rs[wid] = s; rs2[wid] = s2; }
  __syncthreads();
  if (threadIdx.x == 0) {
    part[blockIdx.x * 2 + 0] = rs[0] + rs[1] + rs[2] + rs[3];
    part[blockIdx.x * 2 + 1] = rs2[0] + rs2[1] + rs2[2] + rs2[3];
  }
}

// ---- GroupNorm apply -> xnT [b][n][c] bf16: grid 512 = 128 pairs x 4 n-quarters ----
__global__ __launch_bounds__(256) void gn_apply(const float* __restrict__ x,
    const float* __restrict__ gw, const float* __restrict__ gb,
    const float* __restrict__ part, unsigned short* __restrict__ xnT) {
  int pair = blockIdx.x >> 2, qd = blockIdx.x & 3;
  int b = pair >> 5, g = pair & 31;
  float s = part[pair * 4 + 0] + part[pair * 4 + 2];
  float s2 = part[pair * 4 + 1] + part[pair * 4 + 3];
  float mean = s / (CPG * NN);
  float inv = rsqrtf(s2 / (CPG * NN) - mean * mean + EPSG);
  const float* xp = x + (size_t)pair * (CPG * NN);
  int n0 = qd * 1024 + threadIdx.x * 4;
  float sc[8], bi[8];
#pragma unroll
  for (int c = 0; c < 8; ++c) {
    float w = gw[g * 8 + c];
    sc[c] = inv * w;
    bi[c] = gb[g * 8 + c] - mean * inv * w;
  }
  unsigned short row[4][8];
#pragma unroll
  for (int c = 0; c < 8; ++c) {
    float4 v = *(const float4*)&xp[(size_t)c * NN + n0];
    row[0][c] = f2bf(v.x * sc[c] + bi[c]);
    row[1][c] = f2bf(v.y * sc[c] + bi[c]);
    row[2][c] = f2bf(v.z * sc[c] + bi[c]);
    row[3][c] = f2bf(v.w * sc[c] + bi[c]);
  }
#pragma unroll
  for (int r = 0; r < 4; ++r)
    *(uint4*)&xnT[((size_t)b * NN + n0 + r) * CC + g * 8] = *(const uint4*)&row[r][0];
}

// ---- QKV projections: qT/kT [b][n][o], v [b][o][n]; grid 512 (mode0: q,k; mode1: v) ----
__global__ __launch_bounds__(256) void qkv(const unsigned short* __restrict__ xnT,
    const unsigned short* __restrict__ wbf,
    const float* __restrict__ bq, const float* __restrict__ bk,
    const float* __restrict__ bv,
    unsigned short* __restrict__ qT, unsigned short* __restrict__ kT,
    unsigned short* __restrict__ vm) {
  const int mode = blockIdx.x >> 8;
  const int b = (blockIdx.x >> 6) & 3, nt = blockIdx.x & 63;
  const int n0 = nt * 64;
  __shared__ unsigned short Xs[64][CC + 8];
  int tid = threadIdx.x;
#pragma unroll
  for (int i = 0; i < 8; ++i) {
    int id = tid + 256 * i;
    int r = id >> 5, ck = id & 31;
    *(uint4*)&Xs[r][ck * 8] = *(const uint4*)&xnT[((size_t)b * NN + n0 + r) * CC + ck * 8];
  }
  __syncthreads();
  int w = tid >> 6, lane = tid & 63;
  int m = lane & 15, q4 = lane >> 4;
  if (mode == 0) {
    bf16x8 xa[8];
#pragma unroll
    for (int k = 0; k < 8; ++k)
      xa[k] = ldfrag(&Xs[w * 16 + m][k * 32 + q4 * 8]);
    for (int sel = 0; sel < 2; ++sel) {
      const unsigned short* W = wbf + (size_t)sel * CC * CC;
      const float* bias = sel ? bk : bq;
      unsigned short* dst = sel ? kT : qT;
      for (int ot = 0; ot < 16; ++ot) {
        f32x4 acc = {0.f, 0.f, 0.f, 0.f};
#pragma unroll
        for (int k = 0; k < 8; ++k) {
          bf16x8 bf = ldfrag(&W[(size_t)(ot * 16 + m) * CC + k * 32 + q4 * 8]);
          acc = mfma16(xa[k], bf, acc);
        }
        int o = ot * 16 + m;
        float bia = bias[o];
#pragma unroll
        for (int r = 0; r < 4; ++r) {
          int n = n0 + w * 16 + q4 * 4 + r;
          dst[((size_t)b * NN + n) * CC + o] = f2bf(acc[r] + bia);
        }
      }
    }
  } else {
    const unsigned short* Wv = wbf + 2 * CC * CC;
    for (int ot = 0; ot < 4; ++ot) {
      int o0 = w * 64 + ot * 16;
      bf16x8 af[8];
#pragma unroll
      for (int k = 0; k < 8; ++k)
        af[k] = ldfrag(&Wv[(size_t)(o0 + m) * CC + k * 32 + q4 * 8]);
#pragma unroll
      for (int nt4 = 0; nt4 < 4; ++nt4) {
        f32x4 acc = {0.f, 0.f, 0.f, 0.f};
#pragma unroll
        for (int k = 0; k < 8; ++k) {
          bf16x8 bfr = ldfrag(&Xs[nt4 * 16 + m][k * 32 + q4 * 8]);
          acc = mfma16(af[k], bfr, acc);
        }
        int n = n0 + nt4 * 16 + m;
#pragma unroll
        for (int r = 0; r < 4; ++r) {
          int o = o0 + q4 * 4 + r;
          vm[((size_t)b * CC + o) * NN + n] = f2bf(acc[r] + bv[o]);
        }
      }
    }
  }
}

__device__ __forceinline__ void load_kv(const unsigned short* __restrict__ kT,
    const unsigned short* __restrict__ vm, int b, int j0, int tid,
    uint4* kb, uint4* vb) {
#pragma unroll
  for (int i = 0; i < 8; ++i) {
    int id = tid + 256 * i;
    int r = id >> 5, ck = id & 31;
    kb[i] = *(const uint4*)&kT[((size_t)b * NN + j0 + r) * CC + ck * 8];
  }
#pragma unroll
  for (int i = 0; i < 8; ++i) {
    int id = tid + 256 * i;
    int c = id >> 3, ck = id & 7;
    vb[i] = *(const uint4*)&vm[((size_t)b * CC + c) * NN + j0 + ck * 8];
  }
}

// ---- flash attention partials: grid 512 = KSPLIT x 4b x 64 itiles ----
__global__ __launch_bounds__(256, 2) void attn(const unsigned short* __restrict__ qT,
    const unsigned short* __restrict__ kT, const unsigned short* __restrict__ vm,
    float* __restrict__ accP, float* __restrict__ mlP) {
  const int s = blockIdx.x >> 8;
  const int b = (blockIdx.x >> 6) & 3, it = blockIdx.x & 63;
  const int i0 = it * 64;
  __shared__ unsigned short Ks[64][CC + 8];
  __shared__ unsigned short Vs[CC][64 + 8];
  __shared__ unsigned short Ps[4][16][64 + 8];
  int tid = threadIdx.x, w = tid >> 6, lane = tid & 63;
  int m = lane & 15, q4 = lane >> 4;
  bf16x8 qa[8];
#pragma unroll
  for (int k = 0; k < 8; ++k)
    qa[k] = ldfrag(&qT[((size_t)b * NN + i0 + w * 16 + m) * CC + k * 32 + q4 * 8]);
  f32x4 acc[16];
#pragma unroll
  for (int i = 0; i < 16; ++i) acc[i] = (f32x4){0.f, 0.f, 0.f, 0.f};
  float mrow[4] = {-1e30f, -1e30f, -1e30f, -1e30f};
  float lrow[4] = {0.f, 0.f, 0.f, 0.f};
  uint4 kb[8], vb[8];
  const int jbase = s * JITERS * 64;
  load_kv(kT, vm, b, jbase, tid, kb, vb);
  for (int jt = 0; jt < JITERS; ++jt) {
    __syncthreads();               // previous tile fully consumed
#pragma unroll
    for (int i = 0; i < 8; ++i) {
      int id = tid + 256 * i;
      *(uint4*)&Ks[id >> 5][(id & 31) * 8] = kb[i];
    }
#pragma unroll
    for (int i = 0; i < 8; ++i) {
      int id = tid + 256 * i;
      *(uint4*)&Vs[id >> 3][(id & 7) * 8] = vb[i];
    }
    __syncthreads();               // staging visible
    if (jt + 1 < JITERS)           // prefetch next tile; vmcnt drains at next store
      load_kv(kT, vm, b, jbase + (jt + 1) * 64, tid, kb, vb);
    f32x4 sv[4];
#pragma unroll
    for (int jt4 = 0; jt4 < 4; ++jt4) {
      f32x4 a = {0.f, 0.f, 0.f, 0.f};
#pragma unroll
      for (int k = 0; k < 8; ++k) {
        bf16x8 kf = ldfrag(&Ks[jt4 * 16 + m][k * 32 + q4 * 8]);
        a = mfma16(qa[k], kf, a);
      }
      sv[jt4] = a;
    }
    float mnew[4], alpha[4];
#pragma unroll
    for (int r = 0; r < 4; ++r) {
      float mx = fmaxf(fmaxf(sv[0][r], sv[1][r]), fmaxf(sv[2][r], sv[3][r]));
#pragma unroll
      for (int o = 8; o; o >>= 1) mx = fmaxf(mx, __shfl_xor(mx, o));
      mnew[r] = fmaxf(mrow[r], mx);
      alpha[r] = exp2f((mrow[r] - mnew[r]) * KLS);
      mrow[r] = mnew[r];
    }
#pragma unroll
    for (int r = 0; r < 4; ++r) {
      float rsum = 0.f;
#pragma unroll
      for (int jt4 = 0; jt4 < 4; ++jt4) {
        float p = exp2f((sv[jt4][r] - mnew[r]) * KLS);
        rsum += p;
        Ps[w][q4 * 4 + r][jt4 * 16 + m] = f2bf(p);
      }
#pragma unroll
      for (int o = 8; o; o >>= 1) rsum += __shfl_xor(rsum, o);
      lrow[r] = lrow[r] * alpha[r] + rsum;
    }
#pragma unroll
    for (int ct = 0; ct < 16; ++ct)
#pragma unroll
      for (int r = 0; r < 4; ++r) acc[ct][r] *= alpha[r];
    // PV: Ps is per-wave private, Vs already sync'd -> no barrier needed
#pragma unroll
    for (int kk = 0; kk < 2; ++kk) {
      bf16x8 pf = ldfrag(&Ps[w][m][kk * 32 + q4 * 8]);
#pragma unroll
      for (int ct = 0; ct < 16; ++ct) {
        bf16x8 vf = ldfrag(&Vs[ct * 16 + m][kk * 32 + q4 * 8]);
        acc[ct] = mfma16(pf, vf, acc[ct]);
      }
    }
  }
#pragma unroll
  for (int r = 0; r < 4; ++r) {
    int i = i0 + w * 16 + q4 * 4 + r;
    size_t rr = ((size_t)s * BB + b) * NN + i;
#pragma unroll
    for (int ct = 0; ct < 16; ++ct)
      accP[rr * CC + ct * 16 + m] = acc[ct][r];
    if (m == 0) {
      mlP[rr * 2 + 0] = mrow[r];
      mlP[rr * 2 + 1] = lrow[r];
    }
  }
}

// ---- combine partials -> oT bf16 [b][i][c]; grid 4096 ----
__global__ __launch_bounds__(256) void comb(const float* __restrict__ accP,
    const float* __restrict__ mlP, unsigned short* __restrict__ oT) {
  int e = (blockIdx.x * 256 + threadIdx.x) * 4;
  int row = e >> 8;
  float m0 = mlP[row * 2], l0 = mlP[row * 2 + 1];
  float m1 = mlP[(BBNN + row) * 2], l1 = mlP[(BBNN + row) * 2 + 1];
  float M = fmaxf(m0, m1);
  float w0 = exp2f((m0 - M) * KLS), w1 = exp2f((m1 - M) * KLS);
  float invd = 1.f / (l0 * w0 + l1 * w1);
  w0 *= invd; w1 *= invd;
  float4 a0 = *(const float4*)&accP[e];
  float4 a1 = *(const float4*)&accP[(size_t)BBNN * CC + e];
  unsigned o0 = f2bf(a0.x * w0 + a1.x * w1) | ((unsigned)f2bf(a0.y * w0 + a1.y * w1) << 16);
  unsigned o1 = f2bf(a0.z * w0 + a1.z * w1) | ((unsigned)f2bf(a0.w * w0 + a1.w * w1) << 16);
  uint2 pk = {o0, o1};
  *(uint2*)&oT[e] = pk;
}

// ---- output projection + bias + residual: grid 512 = 4b x 128 n-tiles of 32 ----
__global__ __launch_bounds__(256) void proj(const unsigned short* __restrict__ oT,
    const unsigned short* __restrict__ Wo, const float* __restrict__ bo,
    const float* __restrict__ x, float* __restrict__ out) {
  const int b = blockIdx.x >> 7, nt = blockIdx.x & 127;
  const int n0 = nt * 32;
  __shared__ unsigned short As[32][CC + 8];
  int tid = threadIdx.x;
#pragma unroll
  for (int i = 0; i < 4; ++i) {
    int id = tid + 256 * i;
    int r = id >> 5, ck = id & 31;
    *(uint4*)&As[r][ck * 8] = *(const uint4*)&oT[((size_t)b * NN + n0 + r) * CC + ck * 8];
  }
  __syncthreads();
  int w = tid >> 6, lane = tid & 63, m = lane & 15, q4 = lane >> 4;
  for (int ot = 0; ot < 4; ++ot) {
    int o0 = w * 64 + ot * 16;
    bf16x8 af[8];
#pragma unroll
    for (int k = 0; k < 8; ++k)
      af[k] = ldfrag(&Wo[(size_t)(o0 + m) * CC + k * 32 + q4 * 8]);
#pragma unroll
    for (int nt4 = 0; nt4 < 2; ++nt4) {
      f32x4 a = {0.f, 0.f, 0.f, 0.f};
#pragma unroll
      for (int k = 0; k < 8; ++k) {
        bf16x8 bf = ldfrag(&As[nt4 * 16 + m][k * 32 + q4 * 8]);
        a = mfma16(af[k], bf, a);
      }
      int n = n0 + nt4 * 16 + m;
#pragma unroll
      for (int r = 0; r < 4; ++r) {
        int o = o0 + q4 * 4 + r;
        size_t idx = ((size_t)b * CC + o) * NN + n;
        out[idx] = x[idx] + bo[o] + a[r];
      }
    }
  }
}

extern "C" void kernel_launch(void* const* d_in, const int* in_sizes, int n_in,
                              void* d_out, int out_size, void* d_ws, size_t ws_size,
                              hipStream_t stream) {
  const float* x  = (const float*)d_in[0];
  const float* gw = (const float*)d_in[1];
  const float* gb = (const float*)d_in[2];
  const float* wq = (const float*)d_in[3];
  const float* bq = (const float*)d_in[4];
  const float* wk = (const float*)d_in[5];
  const float* bk = (const float*)d_in[6];
  const float* wv = (const float*)d_in[7];
  const float* bv = (const float*)d_in[8];
  const float* wo = (const float*)d_in[9];
  const float* bo = (const float*)d_in[10];

  unsigned short* ws  = (unsigned short*)d_ws;
  const size_t M4 = (size_t)BB * NN * CC;   // 4M elems
  unsigned short* xnT = ws;
  unsigned short* qT  = xnT + M4;
  unsigned short* kT  = qT + M4;
  unsigned short* vm  = kT + M4;
  unsigned short* oT  = vm + M4;
  unsigned short* wbf = oT + M4;            // 4 * 65536 bf16
  float* accP = (float*)(wbf + 4 * CC * CC);      // KSPLIT * 4M fp32
  float* mlP  = accP + (size_t)KSPLIT * M4;       // KSPLIT * BBNN * 2 fp32
  float* part = mlP + (size_t)KSPLIT * BBNN * 2;  // 512 fp32

  wcvt<<<dim3(64, 4), 256, 0, stream>>>(wq, wk, wv, wo, wbf);
  gn_stats<<<256, 256, 0, stream>>>(x, part);
  gn_apply<<<512, 256, 0, stream>>>(x, gw, gb, part, xnT);
  qkv<<<512, 256, 0, stream>>>(xnT, wbf, bq, bk, bv, qT, kT, vm);
  attn<<<KSPLIT * BB * 64, 256, 0, stream>>>(qT, kT, vm, accP, mlP);
  comb<<<BBNN * CC / 1024, 256, 0, stream>>>(accP, mlP, oT);
  proj<<<512, 256, 0, stream>>>(oT, wbf + 3 * CC * CC, bo, x, (float*)d_out);
}

// Round 3
// 496.424 us; speedup vs baseline: 1.4301x; 1.0176x over previous
//
#include <hip/hip_runtime.h>
#include <hip/hip_bf16.h>

#define BB 4
#define CC 256
#define NN 4096
#define BBNN (BB * NN)
#define NGROUPS 32
#define CPG 8
#define EPSG 1e-6f
#define SCALE 0.0625f                 // C^-0.5
#define KLS 0.09016844005556021f      // SCALE * log2(e)
#define KSPLIT 2
#define JITERS (64 / KSPLIT)

typedef __bf16 bf16x8 __attribute__((ext_vector_type(8)));
typedef float  f32x4  __attribute__((ext_vector_type(4)));

__device__ __forceinline__ unsigned short f2bf(float f) {
  unsigned u = __builtin_bit_cast(unsigned, f);
  u += 0x7fffu + ((u >> 16) & 1u);
  return (unsigned short)(u >> 16);
}

__device__ __forceinline__ f32x4 mfma16(bf16x8 a, bf16x8 b, f32x4 c) {
  return __builtin_amdgcn_mfma_f32_16x16x32_bf16(a, b, c, 0, 0, 0);
}

__device__ __forceinline__ bf16x8 ldfrag(const unsigned short* p) {
  return __builtin_bit_cast(bf16x8, *(const uint4*)p);
}

// ---- weights fp32 -> bf16 ----
__global__ __launch_bounds__(256) void wcvt(const float* __restrict__ wq,
    const float* __restrict__ wk, const float* __restrict__ wv,
    const float* __restrict__ wo, unsigned short* __restrict__ out) {
  int mat = blockIdx.y;
  const float* s = mat == 0 ? wq : mat == 1 ? wk : mat == 2 ? wv : wo;
  int i = (blockIdx.x * 256 + threadIdx.x) * 4;
  float4 v = *(const float4*)&s[i];
  unsigned short* d = out + (size_t)mat * CC * CC + i;
  d[0] = f2bf(v.x); d[1] = f2bf(v.y); d[2] = f2bf(v.z); d[3] = f2bf(v.w);
}

// ---- GroupNorm stats: grid 256 = 128 (b,g) pairs x 2 halves ----
__global__ __launch_bounds__(256) void gn_stats(const float* __restrict__ x,
                                                float* __restrict__ part) {
  int pair = blockIdx.x >> 1, h = blockIdx.x & 1;
  const float* xp = x + (size_t)pair * (CPG * NN) + (size_t)h * (CPG * NN / 2);
  float s = 0.f, s2 = 0.f;
  for (int i = threadIdx.x; i < CPG * NN / 8; i += 256) {
    float4 v = ((const float4*)xp)[i];
    s += v.x + v.y + v.z + v.w;
    s2 += v.x * v.x + v.y * v.y + v.z * v.z + v.w * v.w;
  }
  for (int o = 32; o; o >>= 1) { s += __shfl_down(s, o); s2 += __shfl_down(s2, o); }
  __shared__ float rs[4], rs2[4];
  int wid = threadIdx.x >> 6, lane = threadIdx.x & 63;
  if (lane == 0) { rs[wid] = s; rs2[wid] = s2; }
  __syncthreads();
  if (threadIdx.x == 0) {
    part[blockIdx.x * 2 + 0] = rs[0] + rs[1] + rs[2] + rs[3];
    part[blockIdx.x * 2 + 1] = rs2[0] + rs2[1] + rs2[2] + rs2[3];
  }
}

// ---- GroupNorm apply -> xnT [b][n][c] bf16: grid 512 = 128 pairs x 4 n-quarters ----
__global__ __launch_bounds__(256) void gn_apply(const float* __restrict__ x,
    const float* __restrict__ gw, const float* __restrict__ gb,
    const float* __restrict__ part, unsigned short* __restrict__ xnT) {
  int pair = blockIdx.x >> 2, qd = blockIdx.x & 3;
  int b = pair >> 5, g = pair & 31;
  float s = part[pair * 4 + 0] + part[pair * 4 + 2];
  float s2 = part[pair * 4 + 1] + part[pair * 4 + 3];
  float mean = s / (CPG * NN);
  float inv = rsqrtf(s2 / (CPG * NN) - mean * mean + EPSG);
  const float* xp = x + (size_t)pair * (CPG * NN);
  int n0 = qd * 1024 + threadIdx.x * 4;
  float sc[8], bi[8];
#pragma unroll
  for (int c = 0; c < 8; ++c) {
    float w = gw[g * 8 + c];
    sc[c] = inv * w;
    bi[c] = gb[g * 8 + c] - mean * inv * w;
  }
  unsigned short row[4][8];
#pragma unroll
  for (int c = 0; c < 8; ++c) {
    float4 v = *(const float4*)&xp[(size_t)c * NN + n0];
    row[0][c] = f2bf(v.x * sc[c] + bi[c]);
    row[1][c] = f2bf(v.y * sc[c] + bi[c]);
    row[2][c] = f2bf(v.z * sc[c] + bi[c]);
    row[3][c] = f2bf(v.w * sc[c] + bi[c]);
  }
#pragma unroll
  for (int r = 0; r < 4; ++r)
    *(uint4*)&xnT[((size_t)b * NN + n0 + r) * CC + g * 8] = *(const uint4*)&row[r][0];
}

// ---- QKV projections: qT/kT [b][n][o], v [b][o][n]; grid 512 ----
// XCD-pinned: low 3 bits = (nhalf*4+b) so K/V for attn group (s,b) are
// produced dirty in the consumer XCD's L2.
__global__ __launch_bounds__(256) void qkv(const unsigned short* __restrict__ xnT,
    const unsigned short* __restrict__ wbf,
    const float* __restrict__ bq, const float* __restrict__ bk,
    const float* __restrict__ bv,
    unsigned short* __restrict__ qT, unsigned short* __restrict__ kT,
    unsigned short* __restrict__ vm) {
  const int sb8 = blockIdx.x & 7;
  const int b = sb8 & 3, nhalf = sb8 >> 2;
  const int t = blockIdx.x >> 3;
  const int mode = t >> 5;
  const int nt = nhalf * 32 + (t & 31);
  const int n0 = nt * 64;
  __shared__ unsigned short Xs[64][CC + 8];
  int tid = threadIdx.x;
#pragma unroll
  for (int i = 0; i < 8; ++i) {
    int id = tid + 256 * i;
    int r = id >> 5, ck = id & 31;
    *(uint4*)&Xs[r][ck * 8] = *(const uint4*)&xnT[((size_t)b * NN + n0 + r) * CC + ck * 8];
  }
  __syncthreads();
  int w = tid >> 6, lane = tid & 63;
  int m = lane & 15, q4 = lane >> 4;
  if (mode == 0) {
    bf16x8 xa[8];
#pragma unroll
    for (int k = 0; k < 8; ++k)
      xa[k] = ldfrag(&Xs[w * 16 + m][k * 32 + q4 * 8]);
    for (int sel = 0; sel < 2; ++sel) {
      const unsigned short* W = wbf + (size_t)sel * CC * CC;
      const float* bias = sel ? bk : bq;
      unsigned short* dst = sel ? kT : qT;
      for (int ot = 0; ot < 16; ++ot) {
        f32x4 acc = {0.f, 0.f, 0.f, 0.f};
#pragma unroll
        for (int k = 0; k < 8; ++k) {
          bf16x8 bf = ldfrag(&W[(size_t)(ot * 16 + m) * CC + k * 32 + q4 * 8]);
          acc = mfma16(xa[k], bf, acc);
        }
        int o = ot * 16 + m;
        float bia = bias[o];
#pragma unroll
        for (int r = 0; r < 4; ++r) {
          int n = n0 + w * 16 + q4 * 4 + r;
          dst[((size_t)b * NN + n) * CC + o] = f2bf(acc[r] + bia);
        }
      }
    }
  } else {
    const unsigned short* Wv = wbf + 2 * CC * CC;
    for (int ot = 0; ot < 4; ++ot) {
      int o0 = w * 64 + ot * 16;
      bf16x8 af[8];
#pragma unroll
      for (int k = 0; k < 8; ++k)
        af[k] = ldfrag(&Wv[(size_t)(o0 + m) * CC + k * 32 + q4 * 8]);
#pragma unroll
      for (int nt4 = 0; nt4 < 4; ++nt4) {
        f32x4 acc = {0.f, 0.f, 0.f, 0.f};
#pragma unroll
        for (int k = 0; k < 8; ++k) {
          bf16x8 bfr = ldfrag(&Xs[nt4 * 16 + m][k * 32 + q4 * 8]);
          acc = mfma16(af[k], bfr, acc);
        }
        int n = n0 + nt4 * 16 + m;
#pragma unroll
        for (int r = 0; r < 4; ++r) {
          int o = o0 + q4 * 4 + r;
          vm[((size_t)b * CC + o) * NN + n] = f2bf(acc[r] + bv[o]);
        }
      }
    }
  }
}

__device__ __forceinline__ void load_kv(const unsigned short* __restrict__ kT,
    const unsigned short* __restrict__ vm, int b, int j0, int tid,
    uint4* kb, uint4* vb) {
#pragma unroll
  for (int i = 0; i < 8; ++i) {
    int id = tid + 256 * i;
    int r = id >> 5, ck = id & 31;
    kb[i] = *(const uint4*)&kT[((size_t)b * NN + j0 + r) * CC + ck * 8];
  }
#pragma unroll
  for (int i = 0; i < 8; ++i) {
    int id = tid + 256 * i;
    int c = id >> 3, ck = id & 7;
    vb[i] = *(const uint4*)&vm[((size_t)b * CC + c) * NN + j0 + ck * 8];
  }
}

// ---- flash attention partials: grid 512 ----
// XCD-pinned: low 3 bits of blockIdx = (s*4+b). All 64 blocks of one (s,b)
// group share one XCD -> their 2.1 MB K/V stream stays L2-resident.
__global__ __launch_bounds__(256, 2) void attn(const unsigned short* __restrict__ qT,
    const unsigned short* __restrict__ kT, const unsigned short* __restrict__ vm,
    float* __restrict__ accP, float* __restrict__ mlP) {
  const int sb8 = blockIdx.x & 7;
  const int s = sb8 >> 2, b = sb8 & 3;
  const int it = blockIdx.x >> 3;
  const int i0 = it * 64;
  __shared__ unsigned short Ks[64][CC + 8];
  __shared__ unsigned short Vs[CC][64 + 8];
  __shared__ unsigned short Ps[4][16][64 + 8];
  int tid = threadIdx.x, w = tid >> 6, lane = tid & 63;
  int m = lane & 15, q4 = lane >> 4;
  bf16x8 qa[8];
#pragma unroll
  for (int k = 0; k < 8; ++k)
    qa[k] = ldfrag(&qT[((size_t)b * NN + i0 + w * 16 + m) * CC + k * 32 + q4 * 8]);
  f32x4 acc[16];
#pragma unroll
  for (int i = 0; i < 16; ++i) acc[i] = (f32x4){0.f, 0.f, 0.f, 0.f};
  float mrow[4] = {-1e30f, -1e30f, -1e30f, -1e30f};
  float lrow[4] = {0.f, 0.f, 0.f, 0.f};
  uint4 kb[8], vb[8];
  const int jbase = s * JITERS * 64;
  load_kv(kT, vm, b, jbase, tid, kb, vb);
  for (int jt = 0; jt < JITERS; ++jt) {
    __syncthreads();               // previous tile fully consumed
#pragma unroll
    for (int i = 0; i < 8; ++i) {
      int id = tid + 256 * i;
      *(uint4*)&Ks[id >> 5][(id & 31) * 8] = kb[i];
    }
#pragma unroll
    for (int i = 0; i < 8; ++i) {
      int id = tid + 256 * i;
      *(uint4*)&Vs[id >> 3][(id & 7) * 8] = vb[i];
    }
    __syncthreads();               // staging visible
    if (jt + 1 < JITERS)           // prefetch next tile
      load_kv(kT, vm, b, jbase + (jt + 1) * 64, tid, kb, vb);
    f32x4 sv[4];
#pragma unroll
    for (int jt4 = 0; jt4 < 4; ++jt4) {
      f32x4 a = {0.f, 0.f, 0.f, 0.f};
#pragma unroll
      for (int k = 0; k < 8; ++k) {
        bf16x8 kf = ldfrag(&Ks[jt4 * 16 + m][k * 32 + q4 * 8]);
        a = mfma16(qa[k], kf, a);
      }
      sv[jt4] = a;
    }
    float mnew[4], alpha[4];
#pragma unroll
    for (int r = 0; r < 4; ++r) {
      float mx = fmaxf(fmaxf(sv[0][r], sv[1][r]), fmaxf(sv[2][r], sv[3][r]));
#pragma unroll
      for (int o = 8; o; o >>= 1) mx = fmaxf(mx, __shfl_xor(mx, o));
      mnew[r] = fmaxf(mrow[r], mx);
      alpha[r] = exp2f((mrow[r] - mnew[r]) * KLS);
      mrow[r] = mnew[r];
    }
#pragma unroll
    for (int r = 0; r < 4; ++r) {
      float rsum = 0.f;
#pragma unroll
      for (int jt4 = 0; jt4 < 4; ++jt4) {
        float p = exp2f((sv[jt4][r] - mnew[r]) * KLS);
        rsum += p;
        Ps[w][q4 * 4 + r][jt4 * 16 + m] = f2bf(p);
      }
#pragma unroll
      for (int o = 8; o; o >>= 1) rsum += __shfl_xor(rsum, o);
      lrow[r] = lrow[r] * alpha[r] + rsum;
    }
#pragma unroll
    for (int ct = 0; ct < 16; ++ct)
#pragma unroll
      for (int r = 0; r < 4; ++r) acc[ct][r] *= alpha[r];
    // PV: Ps is per-wave private, Vs already sync'd -> no barrier needed
#pragma unroll
    for (int kk = 0; kk < 2; ++kk) {
      bf16x8 pf = ldfrag(&Ps[w][m][kk * 32 + q4 * 8]);
#pragma unroll
      for (int ct = 0; ct < 16; ++ct) {
        bf16x8 vf = ldfrag(&Vs[ct * 16 + m][kk * 32 + q4 * 8]);
        acc[ct] = mfma16(pf, vf, acc[ct]);
      }
    }
  }
#pragma unroll
  for (int r = 0; r < 4; ++r) {
    int i = i0 + w * 16 + q4 * 4 + r;
    size_t rr = ((size_t)s * BB + b) * NN + i;
#pragma unroll
    for (int ct = 0; ct < 16; ++ct)
      accP[rr * CC + ct * 16 + m] = acc[ct][r];
    if (m == 0) {
      mlP[rr * 2 + 0] = mrow[r];
      mlP[rr * 2 + 1] = lrow[r];
    }
  }
}

// ---- combine partials -> oT bf16 [b][i][c]; grid 4096 ----
__global__ __launch_bounds__(256) void comb(const float* __restrict__ accP,
    const float* __restrict__ mlP, unsigned short* __restrict__ oT) {
  int e = (blockIdx.x * 256 + threadIdx.x) * 4;
  int row = e >> 8;
  float m0 = mlP[row * 2], l0 = mlP[row * 2 + 1];
  float m1 = mlP[(BBNN + row) * 2], l1 = mlP[(BBNN + row) * 2 + 1];
  float M = fmaxf(m0, m1);
  float w0 = exp2f((m0 - M) * KLS), w1 = exp2f((m1 - M) * KLS);
  float invd = 1.f / (l0 * w0 + l1 * w1);
  w0 *= invd; w1 *= invd;
  float4 a0 = *(const float4*)&accP[e];
  float4 a1 = *(const float4*)&accP[(size_t)BBNN * CC + e];
  unsigned o0 = f2bf(a0.x * w0 + a1.x * w1) | ((unsigned)f2bf(a0.y * w0 + a1.y * w1) << 16);
  unsigned o1 = f2bf(a0.z * w0 + a1.z * w1) | ((unsigned)f2bf(a0.w * w0 + a1.w * w1) << 16);
  uint2 pk = {o0, o1};
  *(uint2*)&oT[e] = pk;
}

// ---- output projection + bias + residual: grid 512 = 4b x 128 n-tiles of 32 ----
__global__ __launch_bounds__(256) void proj(const unsigned short* __restrict__ oT,
    const unsigned short* __restrict__ Wo, const float* __restrict__ bo,
    const float* __restrict__ x, float* __restrict__ out) {
  const int b = blockIdx.x >> 7, nt = blockIdx.x & 127;
  const int n0 = nt * 32;
  __shared__ unsigned short As[32][CC + 8];
  int tid = threadIdx.x;
#pragma unroll
  for (int i = 0; i < 4; ++i) {
    int id = tid + 256 * i;
    int r = id >> 5, ck = id & 31;
    *(uint4*)&As[r][ck * 8] = *(const uint4*)&oT[((size_t)b * NN + n0 + r) * CC + ck * 8];
  }
  __syncthreads();
  int w = tid >> 6, lane = tid & 63, m = lane & 15, q4 = lane >> 4;
  for (int ot = 0; ot < 4; ++ot) {
    int o0 = w * 64 + ot * 16;
    bf16x8 af[8];
#pragma unroll
    for (int k = 0; k < 8; ++k)
      af[k] = ldfrag(&Wo[(size_t)(o0 + m) * CC + k * 32 + q4 * 8]);
#pragma unroll
    for (int nt4 = 0; nt4 < 2; ++nt4) {
      f32x4 a = {0.f, 0.f, 0.f, 0.f};
#pragma unroll
      for (int k = 0; k < 8; ++k) {
        bf16x8 bf = ldfrag(&As[nt4 * 16 + m][k * 32 + q4 * 8]);
        a = mfma16(af[k], bf, a);
      }
      int n = n0 + nt4 * 16 + m;
#pragma unroll
      for (int r = 0; r < 4; ++r) {
        int o = o0 + q4 * 4 + r;
        size_t idx = ((size_t)b * CC + o) * NN + n;
        out[idx] = x[idx] + bo[o] + a[r];
      }
    }
  }
}

extern "C" void kernel_launch(void* const* d_in, const int* in_sizes, int n_in,
                              void* d_out, int out_size, void* d_ws, size_t ws_size,
                              hipStream_t stream) {
  const float* x  = (const float*)d_in[0];
  const float* gw = (const float*)d_in[1];
  const float* gb = (const float*)d_in[2];
  const float* wq = (const float*)d_in[3];
  const float* bq = (const float*)d_in[4];
  const float* wk = (const float*)d_in[5];
  const float* bk = (const float*)d_in[6];
  const float* wv = (const float*)d_in[7];
  const float* bv = (const float*)d_in[8];
  const float* wo = (const float*)d_in[9];
  const float* bo = (const float*)d_in[10];

  unsigned short* ws  = (unsigned short*)d_ws;
  const size_t M4 = (size_t)BB * NN * CC;   // 4M elems
  unsigned short* xnT = ws;
  unsigned short* qT  = xnT + M4;
  unsigned short* kT  = qT + M4;
  unsigned short* vm  = kT + M4;
  unsigned short* oT  = vm + M4;
  unsigned short* wbf = oT + M4;            // 4 * 65536 bf16
  float* accP = (float*)(wbf + 4 * CC * CC);      // KSPLIT * 4M fp32
  float* mlP  = accP + (size_t)KSPLIT * M4;       // KSPLIT * BBNN * 2 fp32
  float* part = mlP + (size_t)KSPLIT * BBNN * 2;  // 512 fp32

  wcvt<<<dim3(64, 4), 256, 0, stream>>>(wq, wk, wv, wo, wbf);
  gn_stats<<<256, 256, 0, stream>>>(x, part);
  gn_apply<<<512, 256, 0, stream>>>(x, gw, gb, part, xnT);
  qkv<<<512, 256, 0, stream>>>(xnT, wbf, bq, bk, bv, qT, kT, vm);
  attn<<<KSPLIT * BB * 64, 256, 0, stream>>>(qT, kT, vm, accP, mlP);
  comb<<<BBNN * CC / 1024, 256, 0, stream>>>(accP, mlP, oT);
  proj<<<512, 256, 0, stream>>>(oT, wbf + 3 * CC * CC, bo, x, (float*)d_out);
}

// Round 4
// 307.359 us; speedup vs baseline: 2.3098x; 1.6151x over previous
//
#include <hip/hip_runtime.h>
#include <hip/hip_bf16.h>

#define BB 4
#define CC 256
#define NN 4096
#define BBNN (BB * NN)
#define NGROUPS 32
#define CPG 8
#define EPSG 1e-6f
#define SCALE 0.0625f                 // C^-0.5
#define KLS 0.09016844005556021f      // SCALE * log2(e)
#define KSPLIT 2
#define JITERS (64 / KSPLIT)

typedef __bf16 bf16x8 __attribute__((ext_vector_type(8)));
typedef float  f32x4  __attribute__((ext_vector_type(4)));

__device__ __forceinline__ unsigned short f2bf(float f) {
  unsigned u = __builtin_bit_cast(unsigned, f);
  u += 0x7fffu + ((u >> 16) & 1u);
  return (unsigned short)(u >> 16);
}

__device__ __forceinline__ f32x4 mfma16(bf16x8 a, bf16x8 b, f32x4 c) {
  return __builtin_amdgcn_mfma_f32_16x16x32_bf16(a, b, c, 0, 0, 0);
}

__device__ __forceinline__ bf16x8 ldfrag(const unsigned short* p) {
  return __builtin_bit_cast(bf16x8, *(const uint4*)p);
}

// ---- weights fp32 -> bf16 ----
__global__ __launch_bounds__(256) void wcvt(const float* __restrict__ wq,
    const float* __restrict__ wk, const float* __restrict__ wv,
    const float* __restrict__ wo, unsigned short* __restrict__ out) {
  int mat = blockIdx.y;
  const float* s = mat == 0 ? wq : mat == 1 ? wk : mat == 2 ? wv : wo;
  int i = (blockIdx.x * 256 + threadIdx.x) * 4;
  float4 v = *(const float4*)&s[i];
  unsigned short* d = out + (size_t)mat * CC * CC + i;
  d[0] = f2bf(v.x); d[1] = f2bf(v.y); d[2] = f2bf(v.z); d[3] = f2bf(v.w);
}

// ---- GroupNorm stats: grid 256 = 128 (b,g) pairs x 2 halves ----
__global__ __launch_bounds__(256) void gn_stats(const float* __restrict__ x,
                                                float* __restrict__ part) {
  int pair = blockIdx.x >> 1, h = blockIdx.x & 1;
  const float* xp = x + (size_t)pair * (CPG * NN) + (size_t)h * (CPG * NN / 2);
  float s = 0.f, s2 = 0.f;
  for (int i = threadIdx.x; i < CPG * NN / 8; i += 256) {
    float4 v = ((const float4*)xp)[i];
    s += v.x + v.y + v.z + v.w;
    s2 += v.x * v.x + v.y * v.y + v.z * v.z + v.w * v.w;
  }
  for (int o = 32; o; o >>= 1) { s += __shfl_down(s, o); s2 += __shfl_down(s2, o); }
  __shared__ float rs[4], rs2[4];
  int wid = threadIdx.x >> 6, lane = threadIdx.x & 63;
  if (lane == 0) { rs[wid] = s; rs2[wid] = s2; }
  __syncthreads();
  if (threadIdx.x == 0) {
    part[blockIdx.x * 2 + 0] = rs[0] + rs[1] + rs[2] + rs[3];
    part[blockIdx.x * 2 + 1] = rs2[0] + rs2[1] + rs2[2] + rs2[3];
  }
}

// ---- GroupNorm apply -> xnT [b][n][c] bf16: grid 512 = 128 pairs x 4 n-quarters ----
__global__ __launch_bounds__(256) void gn_apply(const float* __restrict__ x,
    const float* __restrict__ gw, const float* __restrict__ gb,
    const float* __restrict__ part, unsigned short* __restrict__ xnT) {
  int pair = blockIdx.x >> 2, qd = blockIdx.x & 3;
  int b = pair >> 5, g = pair & 31;
  float s = part[pair * 4 + 0] + part[pair * 4 + 2];
  float s2 = part[pair * 4 + 1] + part[pair * 4 + 3];
  float mean = s / (CPG * NN);
  float inv = rsqrtf(s2 / (CPG * NN) - mean * mean + EPSG);
  const float* xp = x + (size_t)pair * (CPG * NN);
  int n0 = qd * 1024 + threadIdx.x * 4;
  float sc[8], bi[8];
#pragma unroll
  for (int c = 0; c < 8; ++c) {
    float w = gw[g * 8 + c];
    sc[c] = inv * w;
    bi[c] = gb[g * 8 + c] - mean * inv * w;
  }
  unsigned short row[4][8];
#pragma unroll
  for (int c = 0; c < 8; ++c) {
    float4 v = *(const float4*)&xp[(size_t)c * NN + n0];
    row[0][c] = f2bf(v.x * sc[c] + bi[c]);
    row[1][c] = f2bf(v.y * sc[c] + bi[c]);
    row[2][c] = f2bf(v.z * sc[c] + bi[c]);
    row[3][c] = f2bf(v.w * sc[c] + bi[c]);
  }
#pragma unroll
  for (int r = 0; r < 4; ++r)
    *(uint4*)&xnT[((size_t)b * NN + n0 + r) * CC + g * 8] = *(const uint4*)&row[r][0];
}

// ---- QKV projections: qT/kT [b][n][o], v [b][o][n]; grid 512 ----
// XCD-pinned: low 3 bits = (nhalf*4+b) so K/V for attn group (s,b) are
// produced dirty in the consumer XCD's L2.
__global__ __launch_bounds__(256) void qkv(const unsigned short* __restrict__ xnT,
    const unsigned short* __restrict__ wbf,
    const float* __restrict__ bq, const float* __restrict__ bk,
    const float* __restrict__ bv,
    unsigned short* __restrict__ qT, unsigned short* __restrict__ kT,
    unsigned short* __restrict__ vm) {
  const int sb8 = blockIdx.x & 7;
  const int b = sb8 & 3, nhalf = sb8 >> 2;
  const int t = blockIdx.x >> 3;
  const int mode = t >> 5;
  const int nt = nhalf * 32 + (t & 31);
  const int n0 = nt * 64;
  __shared__ unsigned short Xs[64][CC + 8];
  int tid = threadIdx.x;
#pragma unroll
  for (int i = 0; i < 8; ++i) {
    int id = tid + 256 * i;
    int r = id >> 5, ck = id & 31;
    *(uint4*)&Xs[r][ck * 8] = *(const uint4*)&xnT[((size_t)b * NN + n0 + r) * CC + ck * 8];
  }
  __syncthreads();
  int w = tid >> 6, lane = tid & 63;
  int m = lane & 15, q4 = lane >> 4;
  if (mode == 0) {
    bf16x8 xa[8];
#pragma unroll
    for (int k = 0; k < 8; ++k)
      xa[k] = ldfrag(&Xs[w * 16 + m][k * 32 + q4 * 8]);
    for (int sel = 0; sel < 2; ++sel) {
      const unsigned short* W = wbf + (size_t)sel * CC * CC;
      const float* bias = sel ? bk : bq;
      unsigned short* dst = sel ? kT : qT;
      for (int ot = 0; ot < 16; ++ot) {
        f32x4 acc = {0.f, 0.f, 0.f, 0.f};
#pragma unroll
        for (int k = 0; k < 8; ++k) {
          bf16x8 bf = ldfrag(&W[(size_t)(ot * 16 + m) * CC + k * 32 + q4 * 8]);
          acc = mfma16(xa[k], bf, acc);
        }
        int o = ot * 16 + m;
        float bia = bias[o];
#pragma unroll
        for (int r = 0; r < 4; ++r) {
          int n = n0 + w * 16 + q4 * 4 + r;
          dst[((size_t)b * NN + n) * CC + o] = f2bf(acc[r] + bia);
        }
      }
    }
  } else {
    const unsigned short* Wv = wbf + 2 * CC * CC;
    for (int ot = 0; ot < 4; ++ot) {
      int o0 = w * 64 + ot * 16;
      bf16x8 af[8];
#pragma unroll
      for (int k = 0; k < 8; ++k)
        af[k] = ldfrag(&Wv[(size_t)(o0 + m) * CC + k * 32 + q4 * 8]);
#pragma unroll
      for (int nt4 = 0; nt4 < 4; ++nt4) {
        f32x4 acc = {0.f, 0.f, 0.f, 0.f};
#pragma unroll
        for (int k = 0; k < 8; ++k) {
          bf16x8 bfr = ldfrag(&Xs[nt4 * 16 + m][k * 32 + q4 * 8]);
          acc = mfma16(af[k], bfr, acc);
        }
        int n = n0 + nt4 * 16 + m;
#pragma unroll
        for (int r = 0; r < 4; ++r) {
          int o = o0 + q4 * 4 + r;
          vm[((size_t)b * CC + o) * NN + n] = f2bf(acc[r] + bv[o]);
        }
      }
    }
  }
}

// ---- flash attention partials: grid 512 ----
// XCD-pinned: low 3 bits of blockIdx = (s*4+b). All 64 blocks of one (s,b)
// group share one XCD -> their 2.1 MB K/V stream stays L2-resident.
// Staging is SYNCHRONOUS: temporaries live only inside the staging phase.
// (Round-2/3 register prefetch held 64 VGPRs across the compute phase ->
// compiler spilled them to scratch every iter -> ~1 GB/dispatch HBM writes.)
__global__ __launch_bounds__(256, 2) void attn(const unsigned short* __restrict__ qT,
    const unsigned short* __restrict__ kT, const unsigned short* __restrict__ vm,
    float* __restrict__ accP, float* __restrict__ mlP) {
  const int sb8 = blockIdx.x & 7;
  const int s = sb8 >> 2, b = sb8 & 3;
  const int it = blockIdx.x >> 3;
  const int i0 = it * 64;
  __shared__ unsigned short Ks[64][CC + 8];
  __shared__ unsigned short Vs[CC][64 + 8];
  __shared__ unsigned short Ps[4][16][64 + 8];
  int tid = threadIdx.x, w = tid >> 6, lane = tid & 63;
  int m = lane & 15, q4 = lane >> 4;
  bf16x8 qa[8];
#pragma unroll
  for (int k = 0; k < 8; ++k)
    qa[k] = ldfrag(&qT[((size_t)b * NN + i0 + w * 16 + m) * CC + k * 32 + q4 * 8]);
  f32x4 acc[16];
#pragma unroll
  for (int i = 0; i < 16; ++i) acc[i] = (f32x4){0.f, 0.f, 0.f, 0.f};
  float mrow[4] = {-1e30f, -1e30f, -1e30f, -1e30f};
  float lrow[4] = {0.f, 0.f, 0.f, 0.f};
  const int jbase = s * JITERS * 64;
  for (int jt = 0; jt < JITERS; ++jt) {
    const int j0 = jbase + jt * 64;
    __syncthreads();               // previous tile fully consumed
    {
      uint4 kb[8], vb[8];
#pragma unroll
      for (int i = 0; i < 8; ++i) {
        int id = tid + 256 * i;
        kb[i] = *(const uint4*)&kT[((size_t)b * NN + j0 + (id >> 5)) * CC + (id & 31) * 8];
      }
#pragma unroll
      for (int i = 0; i < 8; ++i) {
        int id = tid + 256 * i;
        vb[i] = *(const uint4*)&vm[((size_t)b * CC + (id >> 3)) * NN + j0 + (id & 7) * 8];
      }
#pragma unroll
      for (int i = 0; i < 8; ++i) {
        int id = tid + 256 * i;
        *(uint4*)&Ks[id >> 5][(id & 31) * 8] = kb[i];
      }
#pragma unroll
      for (int i = 0; i < 8; ++i) {
        int id = tid + 256 * i;
        *(uint4*)&Vs[id >> 3][(id & 7) * 8] = vb[i];
      }
    }
    __syncthreads();               // staging visible
    f32x4 sv[4];
#pragma unroll
    for (int jt4 = 0; jt4 < 4; ++jt4) {
      f32x4 a = {0.f, 0.f, 0.f, 0.f};
#pragma unroll
      for (int k = 0; k < 8; ++k) {
        bf16x8 kf = ldfrag(&Ks[jt4 * 16 + m][k * 32 + q4 * 8]);
        a = mfma16(qa[k], kf, a);
      }
      sv[jt4] = a;
    }
    float mnew[4], alpha[4];
#pragma unroll
    for (int r = 0; r < 4; ++r) {
      float mx = fmaxf(fmaxf(sv[0][r], sv[1][r]), fmaxf(sv[2][r], sv[3][r]));
#pragma unroll
      for (int o = 8; o; o >>= 1) mx = fmaxf(mx, __shfl_xor(mx, o));
      mnew[r] = fmaxf(mrow[r], mx);
      alpha[r] = exp2f((mrow[r] - mnew[r]) * KLS);
      mrow[r] = mnew[r];
    }
#pragma unroll
    for (int r = 0; r < 4; ++r) {
      float rsum = 0.f;
#pragma unroll
      for (int jt4 = 0; jt4 < 4; ++jt4) {
        float p = exp2f((sv[jt4][r] - mnew[r]) * KLS);
        rsum += p;
        Ps[w][q4 * 4 + r][jt4 * 16 + m] = f2bf(p);
      }
#pragma unroll
      for (int o = 8; o; o >>= 1) rsum += __shfl_xor(rsum, o);
      lrow[r] = lrow[r] * alpha[r] + rsum;
    }
#pragma unroll
    for (int ct = 0; ct < 16; ++ct)
#pragma unroll
      for (int r = 0; r < 4; ++r) acc[ct][r] *= alpha[r];
    // PV: Ps is per-wave private, Vs already sync'd -> no barrier needed
#pragma unroll
    for (int kk = 0; kk < 2; ++kk) {
      bf16x8 pf = ldfrag(&Ps[w][m][kk * 32 + q4 * 8]);
#pragma unroll
      for (int ct = 0; ct < 16; ++ct) {
        bf16x8 vf = ldfrag(&Vs[ct * 16 + m][kk * 32 + q4 * 8]);
        acc[ct] = mfma16(pf, vf, acc[ct]);
      }
    }
  }
#pragma unroll
  for (int r = 0; r < 4; ++r) {
    int i = i0 + w * 16 + q4 * 4 + r;
    size_t rr = ((size_t)s * BB + b) * NN + i;
#pragma unroll
    for (int ct = 0; ct < 16; ++ct)
      accP[rr * CC + ct * 16 + m] = acc[ct][r];
    if (m == 0) {
      mlP[rr * 2 + 0] = mrow[r];
      mlP[rr * 2 + 1] = lrow[r];
    }
  }
}

// ---- combine partials -> oT bf16 [b][i][c]; grid 4096 ----
__global__ __launch_bounds__(256) void comb(const float* __restrict__ accP,
    const float* __restrict__ mlP, unsigned short* __restrict__ oT) {
  int e = (blockIdx.x * 256 + threadIdx.x) * 4;
  int row = e >> 8;
  float m0 = mlP[row * 2], l0 = mlP[row * 2 + 1];
  float m1 = mlP[(BBNN + row) * 2], l1 = mlP[(BBNN + row) * 2 + 1];
  float M = fmaxf(m0, m1);
  float w0 = exp2f((m0 - M) * KLS), w1 = exp2f((m1 - M) * KLS);
  float invd = 1.f / (l0 * w0 + l1 * w1);
  w0 *= invd; w1 *= invd;
  float4 a0 = *(const float4*)&accP[e];
  float4 a1 = *(const float4*)&accP[(size_t)BBNN * CC + e];
  unsigned o0 = f2bf(a0.x * w0 + a1.x * w1) | ((unsigned)f2bf(a0.y * w0 + a1.y * w1) << 16);
  unsigned o1 = f2bf(a0.z * w0 + a1.z * w1) | ((unsigned)f2bf(a0.w * w0 + a1.w * w1) << 16);
  uint2 pk = {o0, o1};
  *(uint2*)&oT[e] = pk;
}

// ---- output projection + bias + residual: grid 512 = 4b x 128 n-tiles of 32 ----
__global__ __launch_bounds__(256) void proj(const unsigned short* __restrict__ oT,
    const unsigned short* __restrict__ Wo, const float* __restrict__ bo,
    const float* __restrict__ x, float* __restrict__ out) {
  const int b = blockIdx.x >> 7, nt = blockIdx.x & 127;
  const int n0 = nt * 32;
  __shared__ unsigned short As[32][CC + 8];
  int tid = threadIdx.x;
#pragma unroll
  for (int i = 0; i < 4; ++i) {
    int id = tid + 256 * i;
    int r = id >> 5, ck = id & 31;
    *(uint4*)&As[r][ck * 8] = *(const uint4*)&oT[((size_t)b * NN + n0 + r) * CC + ck * 8];
  }
  __syncthreads();
  int w = tid >> 6, lane = tid & 63, m = lane & 15, q4 = lane >> 4;
  for (int ot = 0; ot < 4; ++ot) {
    int o0 = w * 64 + ot * 16;
    bf16x8 af[8];
#pragma unroll
    for (int k = 0; k < 8; ++k)
      af[k] = ldfrag(&Wo[(size_t)(o0 + m) * CC + k * 32 + q4 * 8]);
#pragma unroll
    for (int nt4 = 0; nt4 < 2; ++nt4) {
      f32x4 a = {0.f, 0.f, 0.f, 0.f};
#pragma unroll
      for (int k = 0; k < 8; ++k) {
        bf16x8 bf = ldfrag(&As[nt4 * 16 + m][k * 32 + q4 * 8]);
        a = mfma16(af[k], bf, a);
      }
      int n = n0 + nt4 * 16 + m;
#pragma unroll
      for (int r = 0; r < 4; ++r) {
        int o = o0 + q4 * 4 + r;
        size_t idx = ((size_t)b * CC + o) * NN + n;
        out[idx] = x[idx] + bo[o] + a[r];
      }
    }
  }
}

extern "C" void kernel_launch(void* const* d_in, const int* in_sizes, int n_in,
                              void* d_out, int out_size, void* d_ws, size_t ws_size,
                              hipStream_t stream) {
  const float* x  = (const float*)d_in[0];
  const float* gw = (const float*)d_in[1];
  const float* gb = (const float*)d_in[2];
  const float* wq = (const float*)d_in[3];
  const float* bq = (const float*)d_in[4];
  const float* wk = (const float*)d_in[5];
  const float* bk = (const float*)d_in[6];
  const float* wv = (const float*)d_in[7];
  const float* bv = (const float*)d_in[8];
  const float* wo = (const float*)d_in[9];
  const float* bo = (const float*)d_in[10];

  unsigned short* ws  = (unsigned short*)d_ws;
  const size_t M4 = (size_t)BB * NN * CC;   // 4M elems
  unsigned short* xnT = ws;
  unsigned short* qT  = xnT + M4;
  unsigned short* kT  = qT + M4;
  unsigned short* vm  = kT + M4;
  unsigned short* oT  = vm + M4;
  unsigned short* wbf = oT + M4;            // 4 * 65536 bf16
  float* accP = (float*)(wbf + 4 * CC * CC);      // KSPLIT * 4M fp32
  float* mlP  = accP + (size_t)KSPLIT * M4;       // KSPLIT * BBNN * 2 fp32
  float* part = mlP + (size_t)KSPLIT * BBNN * 2;  // 512 fp32

  wcvt<<<dim3(64, 4), 256, 0, stream>>>(wq, wk, wv, wo, wbf);
  gn_stats<<<256, 256, 0, stream>>>(x, part);
  gn_apply<<<512, 256, 0, stream>>>(x, gw, gb, part, xnT);
  qkv<<<512, 256, 0, stream>>>(xnT, wbf, bq, bk, bv, qT, kT, vm);
  attn<<<KSPLIT * BB * 64, 256, 0, stream>>>(qT, kT, vm, accP, mlP);
  comb<<<BBNN * CC / 1024, 256, 0, stream>>>(accP, mlP, oT);
  proj<<<512, 256, 0, stream>>>(oT, wbf + 3 * CC * CC, bo, x, (float*)d_out);
}

// Round 5
// 287.772 us; speedup vs baseline: 2.4670x; 1.0681x over previous
//
#include <hip/hip_runtime.h>
#include <hip/hip_bf16.h>

#define BB 4
#define CC 256
#define NN 4096
#define BBNN (BB * NN)
#define NGROUPS 32
#define CPG 8
#define EPSG 1e-6f
#define SCALE 0.0625f                 // C^-0.5
#define KLS 0.09016844005556021f      // SCALE * log2(e)
#define KSPLIT 2
#define JITERS (64 / KSPLIT)

typedef __bf16 bf16x8 __attribute__((ext_vector_type(8)));
typedef float  f32x4  __attribute__((ext_vector_type(4)));

typedef __attribute__((address_space(1))) const void g_void;
typedef __attribute__((address_space(3))) void l_void;

__device__ __forceinline__ unsigned short f2bf(float f) {
  unsigned u = __builtin_bit_cast(unsigned, f);
  u += 0x7fffu + ((u >> 16) & 1u);
  return (unsigned short)(u >> 16);
}
__device__ __forceinline__ float bf2f(unsigned short s) {
  return __builtin_bit_cast(float, (unsigned)s << 16);
}

__device__ __forceinline__ f32x4 mfma16(bf16x8 a, bf16x8 b, f32x4 c) {
  return __builtin_amdgcn_mfma_f32_16x16x32_bf16(a, b, c, 0, 0, 0);
}

__device__ __forceinline__ bf16x8 ldfrag(const unsigned short* p) {
  return __builtin_bit_cast(bf16x8, *(const uint4*)p);
}

// ---- weights fp32 -> bf16 ----
__global__ __launch_bounds__(256) void wcvt(const float* __restrict__ wq,
    const float* __restrict__ wk, const float* __restrict__ wv,
    const float* __restrict__ wo, unsigned short* __restrict__ out) {
  int mat = blockIdx.y;
  const float* s = mat == 0 ? wq : mat == 1 ? wk : mat == 2 ? wv : wo;
  int i = (blockIdx.x * 256 + threadIdx.x) * 4;
  float4 v = *(const float4*)&s[i];
  unsigned short* d = out + (size_t)mat * CC * CC + i;
  d[0] = f2bf(v.x); d[1] = f2bf(v.y); d[2] = f2bf(v.z); d[3] = f2bf(v.w);
}

// ---- GroupNorm stats ----
__global__ __launch_bounds__(256) void gn_stats(const float* __restrict__ x,
                                                float* __restrict__ part) {
  int pair = blockIdx.x >> 1, h = blockIdx.x & 1;
  const float* xp = x + (size_t)pair * (CPG * NN) + (size_t)h * (CPG * NN / 2);
  float s = 0.f, s2 = 0.f;
  for (int i = threadIdx.x; i < CPG * NN / 8; i += 256) {
    float4 v = ((const float4*)xp)[i];
    s += v.x + v.y + v.z + v.w;
    s2 += v.x * v.x + v.y * v.y + v.z * v.z + v.w * v.w;
  }
  for (int o = 32; o; o >>= 1) { s += __shfl_down(s, o); s2 += __shfl_down(s2, o); }
  __shared__ float rs[4], rs2[4];
  int wid = threadIdx.x >> 6, lane = threadIdx.x & 63;
  if (lane == 0) { rs[wid] = s; rs2[wid] = s2; }
  __syncthreads();
  if (threadIdx.x == 0) {
    part[blockIdx.x * 2 + 0] = rs[0] + rs[1] + rs[2] + rs[3];
    part[blockIdx.x * 2 + 1] = rs2[0] + rs2[1] + rs2[2] + rs2[3];
  }
}

// ---- GroupNorm apply -> xnT [b][n][c] bf16 ----
__global__ __launch_bounds__(256) void gn_apply(const float* __restrict__ x,
    const float* __restrict__ gw, const float* __restrict__ gb,
    const float* __restrict__ part, unsigned short* __restrict__ xnT) {
  int pair = blockIdx.x >> 2, qd = blockIdx.x & 3;
  int b = pair >> 5, g = pair & 31;
  float s = part[pair * 4 + 0] + part[pair * 4 + 2];
  float s2 = part[pair * 4 + 1] + part[pair * 4 + 3];
  float mean = s / (CPG * NN);
  float inv = rsqrtf(s2 / (CPG * NN) - mean * mean + EPSG);
  const float* xp = x + (size_t)pair * (CPG * NN);
  int n0 = qd * 1024 + threadIdx.x * 4;
  float sc[8], bi[8];
#pragma unroll
  for (int c = 0; c < 8; ++c) {
    float w = gw[g * 8 + c];
    sc[c] = inv * w;
    bi[c] = gb[g * 8 + c] - mean * inv * w;
  }
  unsigned short row[4][8];
#pragma unroll
  for (int c = 0; c < 8; ++c) {
    float4 v = *(const float4*)&xp[(size_t)c * NN + n0];
    row[0][c] = f2bf(v.x * sc[c] + bi[c]);
    row[1][c] = f2bf(v.y * sc[c] + bi[c]);
    row[2][c] = f2bf(v.z * sc[c] + bi[c]);
    row[3][c] = f2bf(v.w * sc[c] + bi[c]);
  }
#pragma unroll
  for (int r = 0; r < 4; ++r)
    *(uint4*)&xnT[((size_t)b * NN + n0 + r) * CC + g * 8] = *(const uint4*)&row[r][0];
}

// ---- QKV projections: qT/kT [b][n][o], v [b][o][n]; grid 512, XCD-pinned ----
__global__ __launch_bounds__(256) void qkv(const unsigned short* __restrict__ xnT,
    const unsigned short* __restrict__ wbf,
    const float* __restrict__ bq, const float* __restrict__ bk,
    const float* __restrict__ bv,
    unsigned short* __restrict__ qT, unsigned short* __restrict__ kT,
    unsigned short* __restrict__ vm) {
  const int sb8 = blockIdx.x & 7;
  const int b = sb8 & 3, nhalf = sb8 >> 2;
  const int t = blockIdx.x >> 3;
  const int mode = t >> 5;
  const int nt = nhalf * 32 + (t & 31);
  const int n0 = nt * 64;
  __shared__ unsigned short Xs[64][CC + 8];
  int tid = threadIdx.x;
#pragma unroll
  for (int i = 0; i < 8; ++i) {
    int id = tid + 256 * i;
    int r = id >> 5, ck = id & 31;
    *(uint4*)&Xs[r][ck * 8] = *(const uint4*)&xnT[((size_t)b * NN + n0 + r) * CC + ck * 8];
  }
  __syncthreads();
  int w = tid >> 6, lane = tid & 63;
  int m = lane & 15, q4 = lane >> 4;
  if (mode == 0) {
    bf16x8 xa[8];
#pragma unroll
    for (int k = 0; k < 8; ++k)
      xa[k] = ldfrag(&Xs[w * 16 + m][k * 32 + q4 * 8]);
    for (int sel = 0; sel < 2; ++sel) {
      const unsigned short* W = wbf + (size_t)sel * CC * CC;
      const float* bias = sel ? bk : bq;
      unsigned short* dst = sel ? kT : qT;
      for (int ot = 0; ot < 16; ++ot) {
        f32x4 acc = {0.f, 0.f, 0.f, 0.f};
#pragma unroll
        for (int k = 0; k < 8; ++k) {
          bf16x8 bf = ldfrag(&W[(size_t)(ot * 16 + m) * CC + k * 32 + q4 * 8]);
          acc = mfma16(xa[k], bf, acc);
        }
        int o = ot * 16 + m;
        float bia = bias[o];
#pragma unroll
        for (int r = 0; r < 4; ++r) {
          int n = n0 + w * 16 + q4 * 4 + r;
          dst[((size_t)b * NN + n) * CC + o] = f2bf(acc[r] + bia);
        }
      }
    }
  } else {
    const unsigned short* Wv = wbf + 2 * CC * CC;
    for (int ot = 0; ot < 4; ++ot) {
      int o0 = w * 64 + ot * 16;
      bf16x8 af[8];
#pragma unroll
      for (int k = 0; k < 8; ++k)
        af[k] = ldfrag(&Wv[(size_t)(o0 + m) * CC + k * 32 + q4 * 8]);
#pragma unroll
      for (int nt4 = 0; nt4 < 4; ++nt4) {
        f32x4 acc = {0.f, 0.f, 0.f, 0.f};
#pragma unroll
        for (int k = 0; k < 8; ++k) {
          bf16x8 bfr = ldfrag(&Xs[nt4 * 16 + m][k * 32 + q4 * 8]);
          acc = mfma16(af[k], bfr, acc);
        }
        int n = n0 + nt4 * 16 + m;
#pragma unroll
        for (int r = 0; r < 4; ++r) {
          int o = o0 + q4 * 4 + r;
          vm[((size_t)b * CC + o) * NN + n] = f2bf(acc[r] + bv[o]);
        }
      }
    }
  }
}

// async-DMA stage of one 64-j tile of K and V into swizzled LDS buffers.
// LDS dest is wave-uniform base + lane*16; the XOR swizzle is applied on the
// per-lane GLOBAL source address so fragment reads are conflict-optimal.
__device__ __forceinline__ void stage_kv(const unsigned short* __restrict__ kT,
    const unsigned short* __restrict__ vm, int b, int j0,
    unsigned short* Kbuf, unsigned short* Vbuf, int w, int lane) {
#pragma unroll
  for (int t = 0; t < 4; ++t) {               // K: 2 rows (j) per inst
    int row = w * 8 + t * 2 + (lane >> 5);
    int up = lane & 31;
    int u = (up & 24) | ((up ^ row) & 7);
    const unsigned short* g = &kT[((size_t)b * NN + j0 + row) * CC + u * 8];
    unsigned short* l = &Kbuf[(w * 8 + t * 2) * 256];
    __builtin_amdgcn_global_load_lds((g_void*)g, (l_void*)l, 16, 0, 0);
  }
#pragma unroll
  for (int t = 0; t < 4; ++t) {               // V: 8 rows (c) per inst
    int c = w * 32 + t * 8 + (lane >> 3);
    int u = ((lane & 7) ^ (lane >> 3)) & 7;
    const unsigned short* g = &vm[((size_t)b * CC + c) * NN + j0 + u * 8];
    unsigned short* l = &Vbuf[(w * 32 + t * 8) * 64];
    __builtin_amdgcn_global_load_lds((g_void*)g, (l_void*)l, 16, 0, 0);
  }
}

// ---- flash attention partials: grid 256 = 1/CU, 512 thr, i-block 128 ----
// QK role: wave w owns i-rows [w*16, w*16+16). PV role: wave (ih=w>>2, cq=w&3)
// computes O[ih*64 .. +64][cq*64 .. +64] -> V fragment reads split 4-way.
// K/V double-buffered via global_load_lds issued one iteration ahead.
__global__ __launch_bounds__(512, 1) void attn(const unsigned short* __restrict__ qT,
    const unsigned short* __restrict__ kT, const unsigned short* __restrict__ vm,
    unsigned short* __restrict__ accP, float* __restrict__ mlP) {
  const int sb8 = blockIdx.x & 7;
  const int s = sb8 >> 2, b = sb8 & 3;
  const int it = blockIdx.x >> 3;
  const int i0 = it * 128;
  __shared__ unsigned short Kd[2][64 * 256];   // [buf][j*256 + k~] swizzled
  __shared__ unsigned short Vd[2][256 * 64];   // [buf][c*64 + j~] swizzled
  __shared__ unsigned short Ps[128][72];
  __shared__ float alphaL[128];
  int tid = threadIdx.x, w = tid >> 6, lane = tid & 63;
  int m = lane & 15, q4 = lane >> 4;
  const int ih = w >> 2, cq = w & 3;
  bf16x8 qa[8];
#pragma unroll
  for (int k = 0; k < 8; ++k)
    qa[k] = ldfrag(&qT[((size_t)b * NN + i0 + w * 16 + m) * CC + k * 32 + q4 * 8]);
  f32x4 acc[4][4];
#pragma unroll
  for (int i = 0; i < 4; ++i)
#pragma unroll
    for (int j = 0; j < 4; ++j) acc[i][j] = (f32x4){0.f, 0.f, 0.f, 0.f};
  float mrow[4] = {-1e30f, -1e30f, -1e30f, -1e30f};
  float lrow[4] = {0.f, 0.f, 0.f, 0.f};
  const int jbase = s * JITERS * 64;
  stage_kv(kT, vm, b, jbase, &Kd[0][0], &Vd[0][0], w, lane);
  for (int jt = 0; jt < JITERS; ++jt) {
    __syncthreads();   // buf(jt&1) DMA complete; Ps consumed; buf((jt+1)&1) free
    if (jt + 1 < JITERS)
      stage_kv(kT, vm, b, jbase + (jt + 1) * 64,
               &Kd[(jt + 1) & 1][0], &Vd[(jt + 1) & 1][0], w, lane);
    const unsigned short* Ks = &Kd[jt & 1][0];
    const unsigned short* Vs = &Vd[jt & 1][0];
    // QK^T: S[16i][64j] per wave
    f32x4 sv[4];
#pragma unroll
    for (int jt4 = 0; jt4 < 4; ++jt4) {
      f32x4 a = {0.f, 0.f, 0.f, 0.f};
#pragma unroll
      for (int k = 0; k < 8; ++k) {
        int u = k * 4 + q4;
        int sw = (u & 24) | ((u ^ m) & 7);
        bf16x8 kf = ldfrag(&Ks[(jt4 * 16 + m) * 256 + sw * 8]);
        a = mfma16(qa[k], kf, a);
      }
      sv[jt4] = a;
    }
    float mnew[4], alpha[4];
#pragma unroll
    for (int r = 0; r < 4; ++r) {
      float mx = fmaxf(fmaxf(sv[0][r], sv[1][r]), fmaxf(sv[2][r], sv[3][r]));
#pragma unroll
      for (int o = 8; o; o >>= 1) mx = fmaxf(mx, __shfl_xor(mx, o));
      mnew[r] = fmaxf(mrow[r], mx);
      alpha[r] = exp2f((mrow[r] - mnew[r]) * KLS);
      mrow[r] = mnew[r];
    }
#pragma unroll
    for (int r = 0; r < 4; ++r) {
      float rsum = 0.f;
#pragma unroll
      for (int jt4 = 0; jt4 < 4; ++jt4) {
        float p = exp2f((sv[jt4][r] - mnew[r]) * KLS);
        rsum += p;
        Ps[w * 16 + q4 * 4 + r][jt4 * 16 + m] = f2bf(p);
      }
#pragma unroll
      for (int o = 8; o; o >>= 1) rsum += __shfl_xor(rsum, o);
      lrow[r] = lrow[r] * alpha[r] + rsum;
      if (m == 0) alphaL[w * 16 + q4 * 4 + r] = alpha[r];
    }
    __syncthreads();   // Ps + alpha visible
    // PV: O[64i (ih)][64c (cq)] per wave
    f32x4 av[4];
#pragma unroll
    for (int it4 = 0; it4 < 4; ++it4)
      av[it4] = *(const f32x4*)&alphaL[ih * 64 + it4 * 16 + q4 * 4];
#pragma unroll
    for (int it4 = 0; it4 < 4; ++it4)
#pragma unroll
      for (int ct = 0; ct < 4; ++ct) acc[it4][ct] *= av[it4];
#pragma unroll
    for (int kk = 0; kk < 2; ++kk) {
      bf16x8 vf[4];
#pragma unroll
      for (int ct = 0; ct < 4; ++ct) {
        int u = kk * 4 + q4;
        int sw = (u ^ m) & 7;
        vf[ct] = ldfrag(&Vs[(cq * 64 + ct * 16 + m) * 64 + sw * 8]);
      }
#pragma unroll
      for (int it4 = 0; it4 < 4; ++it4) {
        bf16x8 pf = ldfrag(&Ps[ih * 64 + it4 * 16 + m][kk * 32 + q4 * 8]);
#pragma unroll
        for (int ct = 0; ct < 4; ++ct)
          acc[it4][ct] = mfma16(pf, vf[ct], acc[it4][ct]);
      }
    }
  }
  // epilogue: QK-owner rows write (m,l); PV waves write raw acc as bf16
#pragma unroll
  for (int r = 0; r < 4; ++r) {
    if (m == 0) {
      size_t rq = ((size_t)s * BB + b) * NN + i0 + w * 16 + q4 * 4 + r;
      mlP[rq * 2 + 0] = mrow[r];
      mlP[rq * 2 + 1] = lrow[r];
    }
  }
#pragma unroll
  for (int it4 = 0; it4 < 4; ++it4)
#pragma unroll
    for (int r = 0; r < 4; ++r) {
      size_t rr = ((size_t)s * BB + b) * NN + i0 + ih * 64 + it4 * 16 + q4 * 4 + r;
#pragma unroll
      for (int ct = 0; ct < 4; ++ct)
        accP[rr * CC + cq * 64 + ct * 16 + m] = f2bf(acc[it4][ct][r]);
    }
}

// ---- combine bf16 partials -> oT bf16 [b][i][c]; grid 2048 ----
__global__ __launch_bounds__(256) void comb(const unsigned short* __restrict__ accP,
    const float* __restrict__ mlP, unsigned short* __restrict__ oT) {
  int e = (blockIdx.x * 256 + threadIdx.x) * 8;
  int row = e >> 8;
  float m0 = mlP[row * 2], l0 = mlP[row * 2 + 1];
  float m1 = mlP[(BBNN + row) * 2], l1 = mlP[(BBNN + row) * 2 + 1];
  float M = fmaxf(m0, m1);
  float w0 = exp2f((m0 - M) * KLS), w1 = exp2f((m1 - M) * KLS);
  float invd = 1.f / (l0 * w0 + l1 * w1);
  w0 *= invd; w1 *= invd;
  uint4 a0 = *(const uint4*)&accP[e];
  uint4 a1 = *(const uint4*)&accP[(size_t)BBNN * CC + e];
  const unsigned* p0 = (const unsigned*)&a0;
  const unsigned* p1 = (const unsigned*)&a1;
  unsigned short outv[8];
#pragma unroll
  for (int i = 0; i < 4; ++i) {
    float x0 = bf2f((unsigned short)(p0[i] & 0xffff)) * w0 +
               bf2f((unsigned short)(p1[i] & 0xffff)) * w1;
    float x1 = bf2f((unsigned short)(p0[i] >> 16)) * w0 +
               bf2f((unsigned short)(p1[i] >> 16)) * w1;
    outv[i * 2 + 0] = f2bf(x0);
    outv[i * 2 + 1] = f2bf(x1);
  }
  *(uint4*)&oT[e] = *(const uint4*)&outv[0];
}

// ---- output projection + bias + residual ----
__global__ __launch_bounds__(256) void proj(const unsigned short* __restrict__ oT,
    const unsigned short* __restrict__ Wo, const float* __restrict__ bo,
    const float* __restrict__ x, float* __restrict__ out) {
  const int b = blockIdx.x >> 7, nt = blockIdx.x & 127;
  const int n0 = nt * 32;
  __shared__ unsigned short As[32][CC + 8];
  int tid = threadIdx.x;
#pragma unroll
  for (int i = 0; i < 4; ++i) {
    int id = tid + 256 * i;
    int r = id >> 5, ck = id & 31;
    *(uint4*)&As[r][ck * 8] = *(const uint4*)&oT[((size_t)b * NN + n0 + r) * CC + ck * 8];
  }
  __syncthreads();
  int w = tid >> 6, lane = tid & 63, m = lane & 15, q4 = lane >> 4;
  for (int ot = 0; ot < 4; ++ot) {
    int o0 = w * 64 + ot * 16;
    bf16x8 af[8];
#pragma unroll
    for (int k = 0; k < 8; ++k)
      af[k] = ldfrag(&Wo[(size_t)(o0 + m) * CC + k * 32 + q4 * 8]);
#pragma unroll
    for (int nt4 = 0; nt4 < 2; ++nt4) {
      f32x4 a = {0.f, 0.f, 0.f, 0.f};
#pragma unroll
      for (int k = 0; k < 8; ++k) {
        bf16x8 bf = ldfrag(&As[nt4 * 16 + m][k * 32 + q4 * 8]);
        a = mfma16(af[k], bf, a);
      }
      int n = n0 + nt4 * 16 + m;
#pragma unroll
      for (int r = 0; r < 4; ++r) {
        int o = o0 + q4 * 4 + r;
        size_t idx = ((size_t)b * CC + o) * NN + n;
        out[idx] = x[idx] + bo[o] + a[r];
      }
    }
  }
}

extern "C" void kernel_launch(void* const* d_in, const int* in_sizes, int n_in,
                              void* d_out, int out_size, void* d_ws, size_t ws_size,
                              hipStream_t stream) {
  const float* x  = (const float*)d_in[0];
  const float* gw = (const float*)d_in[1];
  const float* gb = (const float*)d_in[2];
  const float* wq = (const float*)d_in[3];
  const float* bq = (const float*)d_in[4];
  const float* wk = (const float*)d_in[5];
  const float* bk = (const float*)d_in[6];
  const float* wv = (const float*)d_in[7];
  const float* bv = (const float*)d_in[8];
  const float* wo = (const float*)d_in[9];
  const float* bo = (const float*)d_in[10];

  unsigned short* ws  = (unsigned short*)d_ws;
  const size_t M4 = (size_t)BB * NN * CC;   // 4M elems
  unsigned short* xnT = ws;
  unsigned short* qT  = xnT + M4;
  unsigned short* kT  = qT + M4;
  unsigned short* vm  = kT + M4;
  unsigned short* oT  = vm + M4;
  unsigned short* wbf = oT + M4;                   // 4 * 65536 bf16
  unsigned short* accPb = wbf + 4 * CC * CC;       // KSPLIT * 4M bf16
  float* mlP  = (float*)(accPb + (size_t)KSPLIT * M4);  // KSPLIT*BBNN*2 fp32
  float* part = mlP + (size_t)KSPLIT * BBNN * 2;   // 512 fp32

  wcvt<<<dim3(64, 4), 256, 0, stream>>>(wq, wk, wv, wo, wbf);
  gn_stats<<<256, 256, 0, stream>>>(x, part);
  gn_apply<<<512, 256, 0, stream>>>(x, gw, gb, part, xnT);
  qkv<<<512, 256, 0, stream>>>(xnT, wbf, bq, bk, bv, qT, kT, vm);
  attn<<<KSPLIT * BB * 32, 512, 0, stream>>>(qT, kT, vm, accPb, mlP);
  comb<<<BBNN * CC / 2048, 256, 0, stream>>>(accPb, mlP, oT);
  proj<<<512, 256, 0, stream>>>(oT, wbf + 3 * CC * CC, bo, x, (float*)d_out);
}

// Round 6
// 281.168 us; speedup vs baseline: 2.5249x; 1.0235x over previous
//
#include <hip/hip_runtime.h>
#include <hip/hip_bf16.h>

#define BB 4
#define CC 256
#define NN 4096
#define BBNN (BB * NN)
#define NGROUPS 32
#define CPG 8
#define EPSG 1e-6f
#define SCALE 0.0625f                 // C^-0.5
#define KLS 0.09016844005556021f      // SCALE * log2(e)
#define KSPLIT 4
#define JITERS (NN / KSPLIT / 64)     // 16

typedef __bf16 bf16x8 __attribute__((ext_vector_type(8)));
typedef float  f32x4  __attribute__((ext_vector_type(4)));

typedef __attribute__((address_space(1))) const void g_void;
typedef __attribute__((address_space(3))) void l_void;

__device__ __forceinline__ unsigned short f2bf(float f) {
  unsigned u = __builtin_bit_cast(unsigned, f);
  u += 0x7fffu + ((u >> 16) & 1u);
  return (unsigned short)(u >> 16);
}
__device__ __forceinline__ float bf2f(unsigned short s) {
  return __builtin_bit_cast(float, (unsigned)s << 16);
}

__device__ __forceinline__ f32x4 mfma16(bf16x8 a, bf16x8 b, f32x4 c) {
  return __builtin_amdgcn_mfma_f32_16x16x32_bf16(a, b, c, 0, 0, 0);
}
__device__ __forceinline__ f32x4 mfma8(long a, long b, f32x4 c) {
  return __builtin_amdgcn_mfma_f32_16x16x32_fp8_fp8(a, b, c, 0, 0, 0);
}

__device__ __forceinline__ bf16x8 ldfrag(const unsigned short* p) {
  return __builtin_bit_cast(bf16x8, *(const uint4*)p);
}

// ---- weights fp32 -> bf16 ----
__global__ __launch_bounds__(256) void wcvt(const float* __restrict__ wq,
    const float* __restrict__ wk, const float* __restrict__ wv,
    const float* __restrict__ wo, unsigned short* __restrict__ out) {
  int mat = blockIdx.y;
  const float* s = mat == 0 ? wq : mat == 1 ? wk : mat == 2 ? wv : wo;
  int i = (blockIdx.x * 256 + threadIdx.x) * 4;
  float4 v = *(const float4*)&s[i];
  unsigned short* d = out + (size_t)mat * CC * CC + i;
  d[0] = f2bf(v.x); d[1] = f2bf(v.y); d[2] = f2bf(v.z); d[3] = f2bf(v.w);
}

// ---- GroupNorm stats ----
__global__ __launch_bounds__(256) void gn_stats(const float* __restrict__ x,
                                                float* __restrict__ part) {
  int pair = blockIdx.x >> 1, h = blockIdx.x & 1;
  const float* xp = x + (size_t)pair * (CPG * NN) + (size_t)h * (CPG * NN / 2);
  float s = 0.f, s2 = 0.f;
  for (int i = threadIdx.x; i < CPG * NN / 8; i += 256) {
    float4 v = ((const float4*)xp)[i];
    s += v.x + v.y + v.z + v.w;
    s2 += v.x * v.x + v.y * v.y + v.z * v.z + v.w * v.w;
  }
  for (int o = 32; o; o >>= 1) { s += __shfl_down(s, o); s2 += __shfl_down(s2, o); }
  __shared__ float rs[4], rs2[4];
  int wid = threadIdx.x >> 6, lane = threadIdx.x & 63;
  if (lane == 0) { rs[wid] = s; rs2[wid] = s2; }
  __syncthreads();
  if (threadIdx.x == 0) {
    part[blockIdx.x * 2 + 0] = rs[0] + rs[1] + rs[2] + rs[3];
    part[blockIdx.x * 2 + 1] = rs2[0] + rs2[1] + rs2[2] + rs2[3];
  }
}

// ---- GroupNorm apply -> xnT [b][n][c] bf16 ----
__global__ __launch_bounds__(256) void gn_apply(const float* __restrict__ x,
    const float* __restrict__ gw, const float* __restrict__ gb,
    const float* __restrict__ part, unsigned short* __restrict__ xnT) {
  int pair = blockIdx.x >> 2, qd = blockIdx.x & 3;
  int b = pair >> 5, g = pair & 31;
  float s = part[pair * 4 + 0] + part[pair * 4 + 2];
  float s2 = part[pair * 4 + 1] + part[pair * 4 + 3];
  float mean = s / (CPG * NN);
  float inv = rsqrtf(s2 / (CPG * NN) - mean * mean + EPSG);
  const float* xp = x + (size_t)pair * (CPG * NN);
  int n0 = qd * 1024 + threadIdx.x * 4;
  float sc[8], bi[8];
#pragma unroll
  for (int c = 0; c < 8; ++c) {
    float w = gw[g * 8 + c];
    sc[c] = inv * w;
    bi[c] = gb[g * 8 + c] - mean * inv * w;
  }
  unsigned short row[4][8];
#pragma unroll
  for (int c = 0; c < 8; ++c) {
    float4 v = *(const float4*)&xp[(size_t)c * NN + n0];
    row[0][c] = f2bf(v.x * sc[c] + bi[c]);
    row[1][c] = f2bf(v.y * sc[c] + bi[c]);
    row[2][c] = f2bf(v.z * sc[c] + bi[c]);
    row[3][c] = f2bf(v.w * sc[c] + bi[c]);
  }
#pragma unroll
  for (int r = 0; r < 4; ++r)
    *(uint4*)&xnT[((size_t)b * NN + n0 + r) * CC + g * 8] = *(const uint4*)&row[r][0];
}

// ---- QKV projections -> q8/k8 [b][n][c] fp8, v8 [b][c][n] fp8; grid 512 ----
// XCD-pinned: low 3 bits = (s&1)*4 + b (s = j-split of the 64-n tile) so K/V
// land dirty in the consumer attn group's XCD L2.
__global__ __launch_bounds__(256) void qkv(const unsigned short* __restrict__ xnT,
    const unsigned short* __restrict__ wbf,
    const float* __restrict__ bq, const float* __restrict__ bk,
    const float* __restrict__ bv,
    unsigned char* __restrict__ q8, unsigned char* __restrict__ k8,
    unsigned char* __restrict__ v8) {
  const int low = blockIdx.x & 7;
  const int b = low & 3, shalf = low >> 2;
  const int t = blockIdx.x >> 3;
  const int mode = t >> 5;
  const int u = t & 31;
  const int sidx = (u >> 4) * 2 + shalf;
  const int nt = sidx * 16 + (u & 15);
  const int n0 = nt * 64;
  __shared__ unsigned short Xs[64][CC + 8];
  int tid = threadIdx.x;
#pragma unroll
  for (int i = 0; i < 8; ++i) {
    int id = tid + 256 * i;
    int r = id >> 5, ck = id & 31;
    *(uint4*)&Xs[r][ck * 8] = *(const uint4*)&xnT[((size_t)b * NN + n0 + r) * CC + ck * 8];
  }
  __syncthreads();
  int w = tid >> 6, lane = tid & 63;
  int m = lane & 15, q4 = lane >> 4;
  if (mode == 0) {
    bf16x8 xa[8];
#pragma unroll
    for (int k = 0; k < 8; ++k)
      xa[k] = ldfrag(&Xs[w * 16 + m][k * 32 + q4 * 8]);
    for (int sel = 0; sel < 2; ++sel) {
      const unsigned short* W = wbf + (size_t)sel * CC * CC;
      const float* bias = sel ? bk : bq;
      unsigned char* dst = sel ? k8 : q8;
      for (int ot = 0; ot < 16; ++ot) {
        f32x4 acc = {0.f, 0.f, 0.f, 0.f};
#pragma unroll
        for (int k = 0; k < 8; ++k) {
          bf16x8 bf = ldfrag(&W[(size_t)(ot * 16 + m) * CC + k * 32 + q4 * 8]);
          acc = mfma16(xa[k], bf, acc);
        }
        int o = ot * 16 + m;
        float bia = bias[o];
        unsigned pk01 = __builtin_amdgcn_cvt_pk_fp8_f32(acc[0] + bia, acc[1] + bia, 0u, false);
        unsigned pk23 = __builtin_amdgcn_cvt_pk_fp8_f32(acc[2] + bia, acc[3] + bia, 0u, false);
        size_t base = ((size_t)b * NN + n0 + w * 16 + q4 * 4) * CC + o;
        dst[base]          = (unsigned char)(pk01 & 0xff);
        dst[base + CC]     = (unsigned char)((pk01 >> 8) & 0xff);
        dst[base + 2 * CC] = (unsigned char)(pk23 & 0xff);
        dst[base + 3 * CC] = (unsigned char)((pk23 >> 8) & 0xff);
      }
    }
  } else {
    const unsigned short* Wv = wbf + 2 * CC * CC;
    for (int ot = 0; ot < 4; ++ot) {
      int o0 = w * 64 + ot * 16;
      bf16x8 af[8];
#pragma unroll
      for (int k = 0; k < 8; ++k)
        af[k] = ldfrag(&Wv[(size_t)(o0 + m) * CC + k * 32 + q4 * 8]);
#pragma unroll
      for (int nt4 = 0; nt4 < 4; ++nt4) {
        f32x4 acc = {0.f, 0.f, 0.f, 0.f};
#pragma unroll
        for (int k = 0; k < 8; ++k) {
          bf16x8 bfr = ldfrag(&Xs[nt4 * 16 + m][k * 32 + q4 * 8]);
          acc = mfma16(af[k], bfr, acc);
        }
        int n = n0 + nt4 * 16 + m;
        int o = o0 + q4 * 4;
        unsigned pk01 = __builtin_amdgcn_cvt_pk_fp8_f32(acc[0] + bv[o], acc[1] + bv[o + 1], 0u, false);
        unsigned pk23 = __builtin_amdgcn_cvt_pk_fp8_f32(acc[2] + bv[o + 2], acc[3] + bv[o + 3], 0u, false);
        size_t base = ((size_t)b * CC + o) * NN + n;
        v8[base]          = (unsigned char)(pk01 & 0xff);
        v8[base + NN]     = (unsigned char)((pk01 >> 8) & 0xff);
        v8[base + 2 * NN] = (unsigned char)(pk23 & 0xff);
        v8[base + 3 * NN] = (unsigned char)((pk23 >> 8) & 0xff);
      }
    }
  }
}

// DMA-stage one 64-j fp8 tile of K (64x256B) and V (256x64B), 16B-block
// XOR-swizzled on the GLOBAL source address (LDS dest = uniform + lane*16).
__device__ __forceinline__ void stage8(const unsigned char* __restrict__ kp,
    const unsigned char* __restrict__ vp, int j0,
    unsigned char* Kb, unsigned char* Vb, int tid) {
  int w = tid >> 6;
#pragma unroll
  for (int t = 0; t < 2; ++t) {
    int item = t * 512 + tid;
    int row = item >> 4, d16 = item & 15;
    int s16 = d16 ^ ((row >> 1) & 7);
    const unsigned char* g = kp + (size_t)(j0 + row) * CC + s16 * 16;
    __builtin_amdgcn_global_load_lds((g_void*)g, (l_void*)(Kb + (t * 512 + w * 64) * 16), 16, 0, 0);
  }
#pragma unroll
  for (int t = 0; t < 2; ++t) {
    int item = t * 512 + tid;
    int row = item >> 2, d16 = item & 3;
    int s16 = d16 ^ ((row >> 2) & 3);
    const unsigned char* g = vp + (size_t)row * NN + j0 + s16 * 16;
    __builtin_amdgcn_global_load_lds((g_void*)g, (l_void*)(Vb + (t * 512 + w * 64) * 16), 16, 0, 0);
  }
}

// ---- flash attention fp8: grid 512 = 16 (s,b) groups x 32 itiles, 2 blk/CU ----
__global__ __launch_bounds__(512, 2) void attn(const unsigned char* __restrict__ q8,
    const unsigned char* __restrict__ k8, const unsigned char* __restrict__ v8,
    unsigned short* __restrict__ accP, float* __restrict__ mlP) {
  const int grp = blockIdx.x & 15;
  const int s = grp >> 2, b = grp & 3;
  const int it = blockIdx.x >> 4;
  const int i0 = it * 128;
  __shared__ unsigned char Kd[2][64 * 256];
  __shared__ unsigned char Vd[2][256 * 64];
  __shared__ unsigned char Ps[128 * 64];
  __shared__ float alphaL[128];
  int tid = threadIdx.x, w = tid >> 6, lane = tid & 63;
  int m = lane & 15, q4 = lane >> 4;
  const int ih = w >> 2, cq = w & 3;
  const unsigned char* kp = k8 + (size_t)b * NN * CC;
  const unsigned char* vp = v8 + (size_t)b * CC * NN;
  long qa[8];
#pragma unroll
  for (int kc = 0; kc < 8; ++kc)
    qa[kc] = __builtin_bit_cast(long,
        *(const uint2*)&q8[((size_t)b * NN + i0 + w * 16 + m) * CC + kc * 32 + q4 * 8]);
  f32x4 acc[4][4];
#pragma unroll
  for (int i = 0; i < 4; ++i)
#pragma unroll
    for (int j = 0; j < 4; ++j) acc[i][j] = (f32x4){0.f, 0.f, 0.f, 0.f};
  float mrow[4] = {-1e30f, -1e30f, -1e30f, -1e30f};
  float lrow[4] = {0.f, 0.f, 0.f, 0.f};
  const int jbase = s * JITERS * 64;
  stage8(kp, vp, jbase, Kd[0], Vd[0], tid);

  auto step = [&](int jt, int buf) {
    __syncthreads();               // DMA(buf) done; Ps consumed; buf^1 free
    if (jt + 1 < JITERS)
      stage8(kp, vp, jbase + (jt + 1) * 64, Kd[buf ^ 1], Vd[buf ^ 1], tid);
    const unsigned char* Ks = Kd[buf];
    const unsigned char* Vs = Vd[buf];
    f32x4 sv[4];
#pragma unroll
    for (int jt4 = 0; jt4 < 4; ++jt4) {
      f32x4 a = {0.f, 0.f, 0.f, 0.f};
#pragma unroll
      for (int kc = 0; kc < 8; ++kc) {
        long kf = *(const long*)&Ks[(jt4 * 16 + m) * 256 + (((kc * 4 + q4) ^ (m & 14)) * 8)];
        a = mfma8(qa[kc], kf, a);
      }
      sv[jt4] = a;
    }
    float mnew[4], alpha[4];
#pragma unroll
    for (int r = 0; r < 4; ++r) {
      float mx = fmaxf(fmaxf(sv[0][r], sv[1][r]), fmaxf(sv[2][r], sv[3][r]));
#pragma unroll
      for (int o = 8; o; o >>= 1) mx = fmaxf(mx, __shfl_xor(mx, o));
      mnew[r] = fmaxf(mrow[r], mx);
      alpha[r] = exp2f((mrow[r] - mnew[r]) * KLS);
      mrow[r] = mnew[r];
    }
#pragma unroll
    for (int r = 0; r < 4; ++r) {
      float p0 = exp2f((sv[0][r] - mnew[r]) * KLS);
      float p1 = exp2f((sv[1][r] - mnew[r]) * KLS);
      float p2 = exp2f((sv[2][r] - mnew[r]) * KLS);
      float p3 = exp2f((sv[3][r] - mnew[r]) * KLS);
      float rsum = (p0 + p1) + (p2 + p3);
      unsigned pk01 = __builtin_amdgcn_cvt_pk_fp8_f32(p0, p1, 0u, false);
      unsigned pk23 = __builtin_amdgcn_cvt_pk_fp8_f32(p2, p3, 0u, false);
      int prow = w * 16 + q4 * 4 + r;
      unsigned char* pb = &Ps[prow * 64 + (m & 7)];
      int mh = m >> 3, q2 = q4 * 2;
      pb[((0 + mh) ^ q2) * 8] = (unsigned char)(pk01 & 0xff);
      pb[((2 + mh) ^ q2) * 8] = (unsigned char)((pk01 >> 8) & 0xff);
      pb[((4 + mh) ^ q2) * 8] = (unsigned char)(pk23 & 0xff);
      pb[((6 + mh) ^ q2) * 8] = (unsigned char)((pk23 >> 8) & 0xff);
#pragma unroll
      for (int o = 8; o; o >>= 1) rsum += __shfl_xor(rsum, o);
      lrow[r] = lrow[r] * alpha[r] + rsum;
      if (m == 0) alphaL[prow] = alpha[r];
    }
    __syncthreads();               // Ps + alpha visible
    f32x4 av[4];
#pragma unroll
    for (int it4 = 0; it4 < 4; ++it4)
      av[it4] = *(const f32x4*)&alphaL[ih * 64 + it4 * 16 + q4 * 4];
    bool ns = false;
#pragma unroll
    for (int it4 = 0; it4 < 4; ++it4)
#pragma unroll
      for (int r = 0; r < 4; ++r) ns |= (av[it4][r] != 1.0f);
    if (__any(ns)) {
#pragma unroll
      for (int it4 = 0; it4 < 4; ++it4)
#pragma unroll
        for (int ct = 0; ct < 4; ++ct) acc[it4][ct] *= av[it4];
    }
#pragma unroll
    for (int kk = 0; kk < 2; ++kk) {
      long vf[4];
#pragma unroll
      for (int ct = 0; ct < 4; ++ct)
        vf[ct] = *(const long*)&Vs[(cq * 64 + ct * 16 + m) * 64 + (((kk * 4 + q4) ^ ((m >> 1) & 6)) * 8)];
#pragma unroll
      for (int it4 = 0; it4 < 4; ++it4) {
        long pf = *(const long*)&Ps[(ih * 64 + it4 * 16 + m) * 64 + (((kk * 4 + q4) ^ ((m >> 1) & 6)) * 8)];
#pragma unroll
        for (int ct = 0; ct < 4; ++ct)
          acc[it4][ct] = mfma8(pf, vf[ct], acc[it4][ct]);
      }
    }
  };
  for (int jt2 = 0; jt2 < JITERS; jt2 += 2) { step(jt2, 0); step(jt2 + 1, 1); }

#pragma unroll
  for (int r = 0; r < 4; ++r) {
    if (m == 0) {
      size_t rq = ((size_t)s * BB + b) * NN + i0 + w * 16 + q4 * 4 + r;
      mlP[rq * 2 + 0] = mrow[r];
      mlP[rq * 2 + 1] = lrow[r];
    }
  }
#pragma unroll
  for (int it4 = 0; it4 < 4; ++it4)
#pragma unroll
    for (int r = 0; r < 4; ++r) {
      size_t rr = ((size_t)s * BB + b) * NN + i0 + ih * 64 + it4 * 16 + q4 * 4 + r;
#pragma unroll
      for (int ct = 0; ct < 4; ++ct)
        accP[rr * CC + cq * 64 + ct * 16 + m] = f2bf(acc[it4][ct][r]);
    }
}

// ---- combine 4 bf16 partials -> oT bf16 [b][i][c]; grid 2048 ----
__global__ __launch_bounds__(256) void comb(const unsigned short* __restrict__ accP,
    const float* __restrict__ mlP, unsigned short* __restrict__ oT) {
  int e = (blockIdx.x * 256 + threadIdx.x) * 8;
  int row = e >> 8;
  float mv[KSPLIT], lv[KSPLIT], M = -1e30f;
#pragma unroll
  for (int s = 0; s < KSPLIT; ++s) {
    mv[s] = mlP[((size_t)s * BBNN + row) * 2];
    lv[s] = mlP[((size_t)s * BBNN + row) * 2 + 1];
    M = fmaxf(M, mv[s]);
  }
  float wg[KSPLIT], denom = 0.f;
#pragma unroll
  for (int s = 0; s < KSPLIT; ++s) {
    wg[s] = exp2f((mv[s] - M) * KLS);
    denom += lv[s] * wg[s];
  }
  float invd = 1.f / denom;
  float fin[8] = {0.f, 0.f, 0.f, 0.f, 0.f, 0.f, 0.f, 0.f};
#pragma unroll
  for (int s = 0; s < KSPLIT; ++s) {
    uint4 a = *(const uint4*)&accP[(size_t)s * BBNN * CC + e];
    const unsigned* p = (const unsigned*)&a;
    float ws = wg[s] * invd;
#pragma unroll
    for (int i = 0; i < 4; ++i) {
      fin[i * 2 + 0] += bf2f((unsigned short)(p[i] & 0xffff)) * ws;
      fin[i * 2 + 1] += bf2f((unsigned short)(p[i] >> 16)) * ws;
    }
  }
  unsigned short outv[8];
#pragma unroll
  for (int i = 0; i < 8; ++i) outv[i] = f2bf(fin[i]);
  *(uint4*)&oT[e] = *(const uint4*)&outv[0];
}

// ---- output projection + bias + residual ----
__global__ __launch_bounds__(256) void proj(const unsigned short* __restrict__ oT,
    const unsigned short* __restrict__ Wo, const float* __restrict__ bo,
    const float* __restrict__ x, float* __restrict__ out) {
  const int b = blockIdx.x >> 7, nt = blockIdx.x & 127;
  const int n0 = nt * 32;
  __shared__ unsigned short As[32][CC + 8];
  int tid = threadIdx.x;
#pragma unroll
  for (int i = 0; i < 4; ++i) {
    int id = tid + 256 * i;
    int r = id >> 5, ck = id & 31;
    *(uint4*)&As[r][ck * 8] = *(const uint4*)&oT[((size_t)b * NN + n0 + r) * CC + ck * 8];
  }
  __syncthreads();
  int w = tid >> 6, lane = tid & 63, m = lane & 15, q4 = lane >> 4;
  for (int ot = 0; ot < 4; ++ot) {
    int o0 = w * 64 + ot * 16;
    bf16x8 af[8];
#pragma unroll
    for (int k = 0; k < 8; ++k)
      af[k] = ldfrag(&Wo[(size_t)(o0 + m) * CC + k * 32 + q4 * 8]);
#pragma unroll
    for (int nt4 = 0; nt4 < 2; ++nt4) {
      f32x4 a = {0.f, 0.f, 0.f, 0.f};
#pragma unroll
      for (int k = 0; k < 8; ++k) {
        bf16x8 bf = ldfrag(&As[nt4 * 16 + m][k * 32 + q4 * 8]);
        a = mfma16(af[k], bf, a);
      }
      int n = n0 + nt4 * 16 + m;
#pragma unroll
      for (int r = 0; r < 4; ++r) {
        int o = o0 + q4 * 4 + r;
        size_t idx = ((size_t)b * CC + o) * NN + n;
        out[idx] = x[idx] + bo[o] + a[r];
      }
    }
  }
}

extern "C" void kernel_launch(void* const* d_in, const int* in_sizes, int n_in,
                              void* d_out, int out_size, void* d_ws, size_t ws_size,
                              hipStream_t stream) {
  const float* x  = (const float*)d_in[0];
  const float* gw = (const float*)d_in[1];
  const float* gb = (const float*)d_in[2];
  const float* wq = (const float*)d_in[3];
  const float* bq = (const float*)d_in[4];
  const float* wk = (const float*)d_in[5];
  const float* bk = (const float*)d_in[6];
  const float* wv = (const float*)d_in[7];
  const float* bv = (const float*)d_in[8];
  const float* wo = (const float*)d_in[9];
  const float* bo = (const float*)d_in[10];

  const size_t M4 = (size_t)BB * NN * CC;   // 4.19M elems
  unsigned short* xnT = (unsigned short*)d_ws;
  unsigned short* oT  = xnT + M4;
  unsigned short* wbf = oT + M4;                        // 4*65536 bf16
  unsigned short* accPb = wbf + 4 * CC * CC;            // KSPLIT*M4 bf16
  float* mlP  = (float*)(accPb + (size_t)KSPLIT * M4);  // KSPLIT*BBNN*2 f32
  float* part = mlP + (size_t)KSPLIT * BBNN * 2;        // 512 f32
  unsigned char* q8 = (unsigned char*)(part + 512);
  unsigned char* k8 = q8 + M4;
  unsigned char* v8 = k8 + M4;

  wcvt<<<dim3(64, 4), 256, 0, stream>>>(wq, wk, wv, wo, wbf);
  gn_stats<<<256, 256, 0, stream>>>(x, part);
  gn_apply<<<512, 256, 0, stream>>>(x, gw, gb, part, xnT);
  qkv<<<512, 256, 0, stream>>>(xnT, wbf, bq, bk, bv, q8, k8, v8);
  attn<<<KSPLIT * BB * 32, 512, 0, stream>>>(q8, k8, v8, accPb, mlP);
  comb<<<BBNN * CC / 2048, 256, 0, stream>>>(accPb, mlP, oT);
  proj<<<512, 256, 0, stream>>>(oT, wbf + 3 * CC * CC, bo, x, (float*)d_out);
}

// Round 7
// 262.731 us; speedup vs baseline: 2.7021x; 1.0702x over previous
//
#include <hip/hip_runtime.h>
#include <hip/hip_bf16.h>

#define BB 4
#define CC 256
#define NN 4096
#define BBNN (BB * NN)
#define NGROUPS 32
#define CPG 8
#define EPSG 1e-6f
#define QKSCL 0.30028063f             // sqrt(C^-0.5 * log2(e)) folded into q and k
#define KSPLIT 4
#define JITERS (NN / KSPLIT / 64)     // 16

typedef __bf16 bf16x8 __attribute__((ext_vector_type(8)));
typedef float  f32x4  __attribute__((ext_vector_type(4)));

typedef __attribute__((address_space(1))) const void g_void;
typedef __attribute__((address_space(3))) void l_void;

__device__ __forceinline__ unsigned short f2bf(float f) {
  unsigned u = __builtin_bit_cast(unsigned, f);
  u += 0x7fffu + ((u >> 16) & 1u);
  return (unsigned short)(u >> 16);
}
__device__ __forceinline__ float bf2f(unsigned short s) {
  return __builtin_bit_cast(float, (unsigned)s << 16);
}

__device__ __forceinline__ f32x4 mfma16(bf16x8 a, bf16x8 b, f32x4 c) {
  return __builtin_amdgcn_mfma_f32_16x16x32_bf16(a, b, c, 0, 0, 0);
}
__device__ __forceinline__ f32x4 mfma8(long a, long b, f32x4 c) {
  return __builtin_amdgcn_mfma_f32_16x16x32_fp8_fp8(a, b, c, 0, 0, 0);
}

__device__ __forceinline__ bf16x8 ldfrag(const unsigned short* p) {
  return __builtin_bit_cast(bf16x8, *(const uint4*)p);
}

// ---- weights fp32 -> bf16 ----
__global__ __launch_bounds__(256) void wcvt(const float* __restrict__ wq,
    const float* __restrict__ wk, const float* __restrict__ wv,
    const float* __restrict__ wo, unsigned short* __restrict__ out) {
  int mat = blockIdx.y;
  const float* s = mat == 0 ? wq : mat == 1 ? wk : mat == 2 ? wv : wo;
  int i = (blockIdx.x * 256 + threadIdx.x) * 4;
  float4 v = *(const float4*)&s[i];
  unsigned short* d = out + (size_t)mat * CC * CC + i;
  d[0] = f2bf(v.x); d[1] = f2bf(v.y); d[2] = f2bf(v.z); d[3] = f2bf(v.w);
}

// ---- GroupNorm stats ----
__global__ __launch_bounds__(256) void gn_stats(const float* __restrict__ x,
                                                float* __restrict__ part) {
  int pair = blockIdx.x >> 1, h = blockIdx.x & 1;
  const float* xp = x + (size_t)pair * (CPG * NN) + (size_t)h * (CPG * NN / 2);
  float s = 0.f, s2 = 0.f;
  for (int i = threadIdx.x; i < CPG * NN / 8; i += 256) {
    float4 v = ((const float4*)xp)[i];
    s += v.x + v.y + v.z + v.w;
    s2 += v.x * v.x + v.y * v.y + v.z * v.z + v.w * v.w;
  }
  for (int o = 32; o; o >>= 1) { s += __shfl_down(s, o); s2 += __shfl_down(s2, o); }
  __shared__ float rs[4], rs2[4];
  int wid = threadIdx.x >> 6, lane = threadIdx.x & 63;
  if (lane == 0) { rs[wid] = s; rs2[wid] = s2; }
  __syncthreads();
  if (threadIdx.x == 0) {
    part[blockIdx.x * 2 + 0] = rs[0] + rs[1] + rs[2] + rs[3];
    part[blockIdx.x * 2 + 1] = rs2[0] + rs2[1] + rs2[2] + rs2[3];
  }
}

// ---- GroupNorm apply -> xnT [b][n][c] bf16 ----
__global__ __launch_bounds__(256) void gn_apply(const float* __restrict__ x,
    const float* __restrict__ gw, const float* __restrict__ gb,
    const float* __restrict__ part, unsigned short* __restrict__ xnT) {
  int pair = blockIdx.x >> 2, qd = blockIdx.x & 3;
  int b = pair >> 5, g = pair & 31;
  float s = part[pair * 4 + 0] + part[pair * 4 + 2];
  float s2 = part[pair * 4 + 1] + part[pair * 4 + 3];
  float mean = s / (CPG * NN);
  float inv = rsqrtf(s2 / (CPG * NN) - mean * mean + EPSG);
  const float* xp = x + (size_t)pair * (CPG * NN);
  int n0 = qd * 1024 + threadIdx.x * 4;
  float sc[8], bi[8];
#pragma unroll
  for (int c = 0; c < 8; ++c) {
    float w = gw[g * 8 + c];
    sc[c] = inv * w;
    bi[c] = gb[g * 8 + c] - mean * inv * w;
  }
  unsigned short row[4][8];
#pragma unroll
  for (int c = 0; c < 8; ++c) {
    float4 v = *(const float4*)&xp[(size_t)c * NN + n0];
    row[0][c] = f2bf(v.x * sc[c] + bi[c]);
    row[1][c] = f2bf(v.y * sc[c] + bi[c]);
    row[2][c] = f2bf(v.z * sc[c] + bi[c]);
    row[3][c] = f2bf(v.w * sc[c] + bi[c]);
  }
#pragma unroll
  for (int r = 0; r < 4; ++r)
    *(uint4*)&xnT[((size_t)b * NN + n0 + r) * CC + g * 8] = *(const uint4*)&row[r][0];
}

// ---- QKV -> q8/k8 [b][n][c] fp8 (pre-scaled by QKSCL), v8 [b][c][n''] fp8 ----
// v8 spatial index is K-dim-permuted within each 64-block so attn's PV
// B-operand (P^T, packed in registers) and A-operand (V) agree on k-slots.
__global__ __launch_bounds__(256) void qkv(const unsigned short* __restrict__ xnT,
    const unsigned short* __restrict__ wbf,
    const float* __restrict__ bq, const float* __restrict__ bk,
    const float* __restrict__ bv,
    unsigned char* __restrict__ q8, unsigned char* __restrict__ k8,
    unsigned char* __restrict__ v8) {
  const int low = blockIdx.x & 7;
  const int b = low & 3, shalf = low >> 2;
  const int t = blockIdx.x >> 3;
  const int mode = t >> 5;
  const int u = t & 31;
  const int sidx = (u >> 4) * 2 + shalf;
  const int nt = sidx * 16 + (u & 15);
  const int n0 = nt * 64;
  __shared__ unsigned short Xs[64][CC + 8];
  int tid = threadIdx.x;
#pragma unroll
  for (int i = 0; i < 8; ++i) {
    int id = tid + 256 * i;
    int r = id >> 5, ck = id & 31;
    *(uint4*)&Xs[r][ck * 8] = *(const uint4*)&xnT[((size_t)b * NN + n0 + r) * CC + ck * 8];
  }
  __syncthreads();
  int w = tid >> 6, lane = tid & 63;
  int m = lane & 15, q4 = lane >> 4;
  if (mode == 0) {
    bf16x8 xa[8];
#pragma unroll
    for (int k = 0; k < 8; ++k)
      xa[k] = ldfrag(&Xs[w * 16 + m][k * 32 + q4 * 8]);
    for (int sel = 0; sel < 2; ++sel) {
      const unsigned short* W = wbf + (size_t)sel * CC * CC;
      const float* bias = sel ? bk : bq;
      unsigned char* dst = sel ? k8 : q8;
      for (int ot = 0; ot < 16; ++ot) {
        f32x4 acc = {0.f, 0.f, 0.f, 0.f};
#pragma unroll
        for (int k = 0; k < 8; ++k) {
          bf16x8 bf = ldfrag(&W[(size_t)(ot * 16 + m) * CC + k * 32 + q4 * 8]);
          acc = mfma16(xa[k], bf, acc);
        }
        int o = ot * 16 + m;
        float bia = bias[o];
        unsigned pk01 = __builtin_amdgcn_cvt_pk_fp8_f32(
            (acc[0] + bia) * QKSCL, (acc[1] + bia) * QKSCL, 0u, false);
        unsigned pk23 = __builtin_amdgcn_cvt_pk_fp8_f32(
            (acc[2] + bia) * QKSCL, (acc[3] + bia) * QKSCL, 0u, false);
        size_t base = ((size_t)b * NN + n0 + w * 16 + q4 * 4) * CC + o;
        dst[base]          = (unsigned char)(pk01 & 0xff);
        dst[base + CC]     = (unsigned char)((pk01 >> 8) & 0xff);
        dst[base + 2 * CC] = (unsigned char)(pk23 & 0xff);
        dst[base + 3 * CC] = (unsigned char)((pk23 >> 8) & 0xff);
      }
    }
  } else {
    const unsigned short* Wv = wbf + 2 * CC * CC;
    for (int ot = 0; ot < 4; ++ot) {
      int o0 = w * 64 + ot * 16;
      bf16x8 af[8];
#pragma unroll
      for (int k = 0; k < 8; ++k)
        af[k] = ldfrag(&Wv[(size_t)(o0 + m) * CC + k * 32 + q4 * 8]);
#pragma unroll
      for (int nt4 = 0; nt4 < 4; ++nt4) {
        f32x4 acc = {0.f, 0.f, 0.f, 0.f};
#pragma unroll
        for (int k = 0; k < 8; ++k) {
          bf16x8 bfr = ldfrag(&Xs[nt4 * 16 + m][k * 32 + q4 * 8]);
          acc = mfma16(af[k], bfr, acc);
        }
        // K-dim permutation within the 64-block: j bits (5..0) -> j''
        int j = nt4 * 16 + m;
        int jp = (j & 0x23) | ((j & 0x0C) << 1) | ((j & 0x10) >> 2);
        int n = n0 + jp;
        int o = o0 + q4 * 4;
        unsigned pk01 = __builtin_amdgcn_cvt_pk_fp8_f32(acc[0] + bv[o], acc[1] + bv[o + 1], 0u, false);
        unsigned pk23 = __builtin_amdgcn_cvt_pk_fp8_f32(acc[2] + bv[o + 2], acc[3] + bv[o + 3], 0u, false);
        size_t base = ((size_t)b * CC + o) * NN + n;
        v8[base]          = (unsigned char)(pk01 & 0xff);
        v8[base + NN]     = (unsigned char)((pk01 >> 8) & 0xff);
        v8[base + 2 * NN] = (unsigned char)(pk23 & 0xff);
        v8[base + 3 * NN] = (unsigned char)((pk23 >> 8) & 0xff);
      }
    }
  }
}

// DMA one 64-j fp8 tile: K 64x256B rows (16B granule XOR (j>>1)&7),
// V 256x64B rows (16B granule XOR c&3). 256 threads, 8 insts each.
__device__ __forceinline__ void stage8(const unsigned char* __restrict__ kp,
    const unsigned char* __restrict__ vp, int j0,
    unsigned char* Kb, unsigned char* Vb, int tid) {
#pragma unroll
  for (int t = 0; t < 4; ++t) {
    int item = t * 256 + tid;
    int row = item >> 4, d16 = item & 15;
    int s16 = d16 ^ ((row >> 1) & 7);
    const unsigned char* g = kp + (size_t)(j0 + row) * CC + s16 * 16;
    __builtin_amdgcn_global_load_lds((g_void*)g, (l_void*)(Kb + item * 16), 16, 0, 0);
  }
#pragma unroll
  for (int t = 0; t < 4; ++t) {
    int item = t * 256 + tid;
    int row = item >> 2, gl = item & 3;
    int gg = gl ^ (row & 3);
    const unsigned char* g = vp + (size_t)row * NN + j0 + gg * 16;
    __builtin_amdgcn_global_load_lds((g_void*)g, (l_void*)(Vb + item * 16), 16, 0, 0);
  }
}

// ---- flash attention, S^T form: grid 1024 = 16 (s,b) x 64 itiles, 256 thr ----
// mfma8(kf,qa) -> S^T[j][i]: softmax stats are per-lane scalars (i = lane&15),
// P^T repacks to fp8 in-register as the PV B-operand (V pre-permuted in K-dim).
// One barrier per step; O^T transposed via LDS once at epilogue.
__global__ __launch_bounds__(256, 2) void attn(const unsigned char* __restrict__ q8,
    const unsigned char* __restrict__ k8, const unsigned char* __restrict__ v8,
    unsigned short* __restrict__ accP, float* __restrict__ mlP) {
  const int grp = blockIdx.x & 15;
  const int s = grp >> 2, b = grp & 3;
  const int it = blockIdx.x >> 4;
  const int i0 = it * 64;
  __shared__ __align__(16) unsigned char pool[65536];
  unsigned char* Kd0 = pool;
  unsigned char* Kd1 = pool + 16384;
  unsigned char* Vd0 = pool + 32768;
  unsigned char* Vd1 = pool + 49152;
  int tid = threadIdx.x, w = tid >> 6, lane = tid & 63;
  int m = lane & 15, q4 = lane >> 4;
  int q4h = q4 >> 1, q4l = q4 & 1;
  const unsigned char* kp = k8 + (size_t)b * NN * CC;
  const unsigned char* vp = v8 + (size_t)b * CC * NN;
  long qa[8];
#pragma unroll
  for (int kc = 0; kc < 8; ++kc)
    qa[kc] = *(const long*)&q8[((size_t)b * NN + i0 + w * 16 + m) * CC + kc * 32 + q4 * 8];
  f32x4 acc[16];
#pragma unroll
  for (int i = 0; i < 16; ++i) acc[i] = (f32x4){0.f, 0.f, 0.f, 0.f};
  float mrow = -1e30f, lrow = 0.f;
  const int jbase = s * (NN / KSPLIT);
  stage8(kp, vp, jbase, Kd0, Vd0, tid);
  for (int jt = 0; jt < JITERS; ++jt) {
    __syncthreads();               // drains DMA(buf) + all waves done with buf^1
    if (jt + 1 < JITERS)
      stage8(kp, vp, jbase + (jt + 1) * 64,
             (jt & 1) ? Kd0 : Kd1, (jt & 1) ? Vd0 : Vd1, tid);
    const unsigned char* Ks = (jt & 1) ? Kd1 : Kd0;
    const unsigned char* Vs = (jt & 1) ? Vd1 : Vd0;
    f32x4 sv[4];
#pragma unroll
    for (int jt4 = 0; jt4 < 4; ++jt4) {
      f32x4 a = {0.f, 0.f, 0.f, 0.f};
#pragma unroll
      for (int kc = 0; kc < 8; ++kc) {
        int gl = (kc * 2 + q4h) ^ ((m >> 1) & 7);
        long kf = *(const long*)&Ks[(jt4 * 16 + m) * 256 + gl * 16 + q4l * 8];
        a = mfma8(kf, qa[kc], a);
      }
      sv[jt4] = a;
    }
    float mx = fmaxf(fmaxf(fmaxf(sv[0][0], sv[0][1]), fmaxf(sv[0][2], sv[0][3])),
                     fmaxf(fmaxf(sv[1][0], sv[1][1]), fmaxf(sv[1][2], sv[1][3])));
    mx = fmaxf(mx, fmaxf(fmaxf(fmaxf(sv[2][0], sv[2][1]), fmaxf(sv[2][2], sv[2][3])),
                         fmaxf(fmaxf(sv[3][0], sv[3][1]), fmaxf(sv[3][2], sv[3][3]))));
    mx = fmaxf(mx, __shfl_xor(mx, 16));
    mx = fmaxf(mx, __shfl_xor(mx, 32));
    float mnew = fmaxf(mrow, mx);
    float alpha = exp2f(mrow - mnew);
    mrow = mnew;
    float rsum = 0.f;
    unsigned pd[4];
#pragma unroll
    for (int jt4 = 0; jt4 < 4; ++jt4) {
      float e0 = exp2f(sv[jt4][0] - mnew);
      float e1 = exp2f(sv[jt4][1] - mnew);
      float e2 = exp2f(sv[jt4][2] - mnew);
      float e3 = exp2f(sv[jt4][3] - mnew);
      rsum += (e0 + e1) + (e2 + e3);
      unsigned d = __builtin_amdgcn_cvt_pk_fp8_f32(e0, e1, 0u, false);
      pd[jt4] = __builtin_amdgcn_cvt_pk_fp8_f32(e2, e3, d, true);
    }
    rsum += __shfl_xor(rsum, 16);
    rsum += __shfl_xor(rsum, 32);
    lrow = lrow * alpha + rsum;
    if (__any(alpha != 1.0f)) {
#pragma unroll
      for (int ct = 0; ct < 16; ++ct) acc[ct] *= alpha;
    }
    int voff = ((q4h) ^ (m & 3)) * 16 + q4l * 8;          // p=0
    int voff1 = ((2 + q4h) ^ (m & 3)) * 16 + q4l * 8;     // p=1
#pragma unroll
    for (int p = 0; p < 2; ++p) {
      uint2 pu = {pd[2 * p], pd[2 * p + 1]};
      long pT = __builtin_bit_cast(long, pu);
      int vo = p ? voff1 : voff;
#pragma unroll
      for (int ct = 0; ct < 16; ++ct) {
        long vf = *(const long*)&Vs[(ct * 16 + m) * 64 + vo];
        acc[ct] = mfma8(vf, pT, acc[ct]);
      }
    }
  }
  // epilogue: per-lane (i = m) stats; O^T -> LDS transpose -> coalesced store
  size_t rq = (size_t)(s * BB + b) * NN + i0 + w * 16 + m;
  if (q4 == 0) {
    mlP[rq * 2 + 0] = mrow;
    mlP[rq * 2 + 1] = lrow;
  }
  __syncthreads();
  unsigned short* tp = (unsigned short*)pool;   // 64 rows x 260 shorts
#pragma unroll
  for (int ct = 0; ct < 16; ++ct) {
    unsigned lo = f2bf(acc[ct][0]) | ((unsigned)f2bf(acc[ct][1]) << 16);
    unsigned hi = f2bf(acc[ct][2]) | ((unsigned)f2bf(acc[ct][3]) << 16);
    uint2 pk = {lo, hi};
    *(uint2*)&tp[(w * 16 + m) * 260 + ct * 16 + q4 * 4] = pk;
  }
  __syncthreads();
#pragma unroll
  for (int u = 0; u < 8; ++u) {
    int id = u * 256 + tid;
    int row = id >> 5, ck = id & 31;
    uint4 v = *(const uint4*)&tp[row * 260 + ck * 8];
    *(uint4*)&accP[((size_t)(s * BB + b) * NN + i0 + row) * CC + ck * 8] = v;
  }
}

// ---- output projection + combine partials + bias + residual; grid 512 ----
__global__ __launch_bounds__(256) void proj(const unsigned short* __restrict__ accP,
    const float* __restrict__ mlP, const unsigned short* __restrict__ Wo,
    const float* __restrict__ bo, const float* __restrict__ x,
    float* __restrict__ out) {
  const int b = blockIdx.x >> 7, nt = blockIdx.x & 127;
  const int n0 = nt * 32;
  __shared__ unsigned short As[32][CC + 8];
  __shared__ float wr[KSPLIT][36];
  int tid = threadIdx.x;
  if (tid < 32) {
    int n = n0 + tid;
    float mv[KSPLIT], lv[KSPLIT], M = -1e30f;
#pragma unroll
    for (int s = 0; s < KSPLIT; ++s) {
      size_t rq = (size_t)(s * BB + b) * NN + n;
      mv[s] = mlP[rq * 2];
      lv[s] = mlP[rq * 2 + 1];
      M = fmaxf(M, mv[s]);
    }
    float ws[KSPLIT], d = 0.f;
#pragma unroll
    for (int s = 0; s < KSPLIT; ++s) {
      ws[s] = exp2f(mv[s] - M);
      d += lv[s] * ws[s];
    }
    float inv = 1.f / d;
#pragma unroll
    for (int s = 0; s < KSPLIT; ++s) wr[s][tid] = ws[s] * inv;
  }
  __syncthreads();
#pragma unroll
  for (int i = 0; i < 4; ++i) {
    int id = tid + 256 * i;
    int r = id >> 5, ck = id & 31;
    int n = n0 + r;
    float f[8] = {0.f, 0.f, 0.f, 0.f, 0.f, 0.f, 0.f, 0.f};
#pragma unroll
    for (int s = 0; s < KSPLIT; ++s) {
      uint4 a = *(const uint4*)&accP[((size_t)(s * BB + b) * NN + n) * CC + ck * 8];
      const unsigned* p = (const unsigned*)&a;
      float wgt = wr[s][r];
#pragma unroll
      for (int k = 0; k < 4; ++k) {
        f[k * 2 + 0] += bf2f((unsigned short)(p[k] & 0xffff)) * wgt;
        f[k * 2 + 1] += bf2f((unsigned short)(p[k] >> 16)) * wgt;
      }
    }
    unsigned short ov[8];
#pragma unroll
    for (int k = 0; k < 8; ++k) ov[k] = f2bf(f[k]);
    *(uint4*)&As[r][ck * 8] = *(const uint4*)&ov[0];
  }
  __syncthreads();
  int w = tid >> 6, lane = tid & 63, m = lane & 15, q4 = lane >> 4;
  for (int ot = 0; ot < 4; ++ot) {
    int o0 = w * 64 + ot * 16;
    bf16x8 af[8];
#pragma unroll
    for (int k = 0; k < 8; ++k)
      af[k] = ldfrag(&Wo[(size_t)(o0 + m) * CC + k * 32 + q4 * 8]);
#pragma unroll
    for (int nt4 = 0; nt4 < 2; ++nt4) {
      f32x4 a = {0.f, 0.f, 0.f, 0.f};
#pragma unroll
      for (int k = 0; k < 8; ++k) {
        bf16x8 bf = ldfrag(&As[nt4 * 16 + m][k * 32 + q4 * 8]);
        a = mfma16(af[k], bf, a);
      }
      int n = n0 + nt4 * 16 + m;
#pragma unroll
      for (int r = 0; r < 4; ++r) {
        int o = o0 + q4 * 4 + r;
        size_t idx = ((size_t)b * CC + o) * NN + n;
        out[idx] = x[idx] + bo[o] + a[r];
      }
    }
  }
}

extern "C" void kernel_launch(void* const* d_in, const int* in_sizes, int n_in,
                              void* d_out, int out_size, void* d_ws, size_t ws_size,
                              hipStream_t stream) {
  const float* x  = (const float*)d_in[0];
  const float* gw = (const float*)d_in[1];
  const float* gb = (const float*)d_in[2];
  const float* wq = (const float*)d_in[3];
  const float* bq = (const float*)d_in[4];
  const float* wk = (const float*)d_in[5];
  const float* bk = (const float*)d_in[6];
  const float* wv = (const float*)d_in[7];
  const float* bv = (const float*)d_in[8];
  const float* wo = (const float*)d_in[9];
  const float* bo = (const float*)d_in[10];

  const size_t M4 = (size_t)BB * NN * CC;
  unsigned short* xnT = (unsigned short*)d_ws;
  unsigned short* wbf = xnT + M4;                       // 4*65536 bf16
  unsigned short* accPb = wbf + 4 * CC * CC;            // KSPLIT*M4 bf16
  float* mlP  = (float*)(accPb + (size_t)KSPLIT * M4);  // KSPLIT*BBNN*2 f32
  float* part = mlP + (size_t)KSPLIT * BBNN * 2;        // 512 f32
  unsigned char* q8 = (unsigned char*)(part + 512);
  unsigned char* k8 = q8 + M4;
  unsigned char* v8 = k8 + M4;

  wcvt<<<dim3(64, 4), 256, 0, stream>>>(wq, wk, wv, wo, wbf);
  gn_stats<<<256, 256, 0, stream>>>(x, part);
  gn_apply<<<512, 256, 0, stream>>>(x, gw, gb, part, xnT);
  qkv<<<512, 256, 0, stream>>>(xnT, wbf, bq, bk, bv, q8, k8, v8);
  attn<<<KSPLIT * BB * 64, 256, 0, stream>>>(q8, k8, v8, accPb, mlP);
  proj<<<512, 256, 0, stream>>>(accPb, mlP, wbf + 3 * CC * CC, bo, x, (float*)d_out);
}